// Round 13
// baseline (181.795 us; speedup 1.0000x reference)
//
#include <hip/hip_runtime.h>
#include <cstddef>
#include <cstdint>

#define NVOCAB 99999

typedef __attribute__((ext_vector_type(8))) short short8v;
typedef __attribute__((ext_vector_type(4))) short short4v;
typedef __attribute__((ext_vector_type(4))) float f32x4;

__device__ __forceinline__ float sigmoidf_(float x){ return 1.0f/(1.0f + __expf(-x)); }

__device__ __forceinline__ unsigned short bf16rn(float x){
    union { float f; uint32_t u; } v; v.f = x;
    uint32_t r = v.u + 0x7FFFu + ((v.u >> 16) & 1u);
    return (unsigned short)(r >> 16);
}

__device__ __forceinline__ void split_bf16(float x, unsigned short &hi, unsigned short &lo){
    hi = bf16rn(x);
    union { uint32_t u; float f; } hf; hf.u = ((uint32_t)hi) << 16;
    lo = bf16rn(x - hf.f);
}

__device__ __forceinline__ void split8(const float* xs, short8v &h, short8v &l){
    #pragma unroll
    for (int e = 0; e < 8; ++e){
        unsigned short uh, ul;
        split_bf16(xs[e], uh, ul);
        h[e] = (short)uh; l[e] = (short)ul;
    }
}

// ---------------- prep: split weights into B-fragment layout ----------------
__global__ __launch_bounds__(256) void k_prep_wfrag(
    const float* __restrict__ W_in, const float* __restrict__ W_out,
    const float* __restrict__ w_ih, const float* __restrict__ w_hh,
    const float* __restrict__ lp,  const float* __restrict__ W2,
    unsigned short* __restrict__ wo_hi,
    unsigned short* __restrict__ wih_hi,
    unsigned short* __restrict__ whh_hi,
    unsigned short* __restrict__ lp_hi,  unsigned short* __restrict__ lp_lo,
    unsigned short* __restrict__ w2_hi,  unsigned short* __restrict__ w2_lo)
{
    int id = blockIdx.x*256 + threadIdx.x;
    if (id < 4096){
        int lane=id&63, tile=id>>6, nt=tile>>2, ks=tile&3;
        int col=nt*16+(lane&15), k=ks*32+(lane>>4)*8;
        const float* src = (col<128) ? (W_in + (size_t)col*128 + k) : (W_out + (size_t)(col-128)*128 + k);
        float4 f0=*(const float4*)src, f1=*(const float4*)(src+4);
        float xs[8]={f0.x,f0.y,f0.z,f0.w,f1.x,f1.y,f1.z,f1.w};
        short8v h;
        #pragma unroll
        for (int e=0;e<8;++e) h[e]=(short)bf16rn(xs[e]);
        *(short8v*)(wo_hi+(size_t)id*8)=h;
    } else if (id < 16384){
        int t2=id-4096, lane=t2&63, tile=t2>>6, nt=tile>>3, ks=tile&7;
        int col=nt*16+(lane&15), k=ks*32+(lane>>4)*8;
        const float* src = w_ih + (size_t)col*256 + k;
        float4 f0=*(const float4*)src, f1=*(const float4*)(src+4);
        short8v h;
        float xs[8]={f0.x,f0.y,f0.z,f0.w,f1.x,f1.y,f1.z,f1.w};
        #pragma unroll
        for (int e=0;e<8;++e) h[e]=(short)bf16rn(xs[e]);
        *(short8v*)(wih_hi+(size_t)t2*8)=h;
    } else if (id < 22528){
        int t3=id-16384, lane=t3&63, tile=t3>>6, nt=tile>>2, ks=tile&3;
        int col=nt*16+(lane&15), k=ks*32+(lane>>4)*8;
        const float* src = w_hh + (size_t)col*128 + k;
        float4 f0=*(const float4*)src, f1=*(const float4*)(src+4);
        short8v h;
        float xs[8]={f0.x,f0.y,f0.z,f0.w,f1.x,f1.y,f1.z,f1.w};
        #pragma unroll
        for (int e=0;e<8;++e) h[e]=(short)bf16rn(xs[e]);
        *(short8v*)(whh_hi+(size_t)t3*8)=h;
    } else if (id < 26624){
        int t4=id-22528, lane=t4&63, tile=t4>>6, nt=tile>>3, ks=tile&7;
        int col=nt*16+(lane&15), k=ks*32+(lane>>4)*8;
        float xs[8];
        #pragma unroll
        for (int e=0;e<8;++e) xs[e]=lp[(size_t)(k+e)*128 + col];
        short8v h,l; split8(xs,h,l);
        *(short8v*)(lp_hi+(size_t)t4*8)=h; *(short8v*)(lp_lo+(size_t)t4*8)=l;
    } else if (id < 28672){
        int t5=id-26624, lane=t5&63, tile=t5>>6, nt=tile>>2, ks=tile&3;
        int col=nt*16+(lane&15), k=ks*32+(lane>>4)*8;
        const float* src = W2 + (size_t)col*128 + k;
        float4 f0=*(const float4*)src, f1=*(const float4*)(src+4);
        float xs[8]={f0.x,f0.y,f0.z,f0.w,f1.x,f1.y,f1.z,f1.w};
        short8v h,l; split8(xs,h,l);
        *(short8v*)(w2_hi+(size_t)t5*8)=h; *(short8v*)(w2_lo+(size_t)t5*8)=l;
    }
}

// ---------------- fused GNN: gather + hv + bmm + gi/gh GEMM + GRU gate -> hidnew ----------------
union SharedU {
    struct { unsigned short hi[256][72]; } hvT;  // 36864 B (hi-only)
    float inp[64][268];                          // 68608 B
};

__global__ __launch_bounds__(512,1) void k_gnn(
    const int* __restrict__ items, const float* __restrict__ Amat,
    const float* __restrict__ emb,
    const float* __restrict__ b_in, const float* __restrict__ b_out,
    const float* __restrict__ b_iah, const float* __restrict__ b_oah,
    const unsigned short* __restrict__ wo_hi,
    const unsigned short* __restrict__ wih_hi, const unsigned short* __restrict__ whh_hi,
    const float* __restrict__ b_ih, const float* __restrict__ b_hh,
    float* __restrict__ hidnew)
{
    const int t=threadIdx.x, lane=t&63, w=t>>6, bl=blockIdx.x;
    const int mi=w&3, ch=w>>2;
    const int c15=lane&15, g=lane>>4, kg=g*8;
    const int row=mi*16+c15;

    __shared__ int s_items[64];
    __shared__ float s_hid[64][132];
    __shared__ SharedU U;
    __shared__ unsigned short wbuf[2][24][512];

    if (t < 64) s_items[t]=items[bl*64+t];
    __syncthreads();

    {
        int r=t>>3, c0=(t&7)*16;
        const float* src = emb + (size_t)s_items[r]*128 + c0;
        float4 v0=*(const float4*)(src);
        float4 v1=*(const float4*)(src+4);
        float4 v2=*(const float4*)(src+8);
        float4 v3=*(const float4*)(src+12);
        *(float4*)&s_hid[r][c0]   = v0;
        *(float4*)&s_hid[r][c0+4] = v1;
        *(float4*)&s_hid[r][c0+8] = v2;
        *(float4*)&s_hid[r][c0+12]= v3;
    }
    __syncthreads();

    short8v hhi[4], hlo[4];
    #pragma unroll
    for (int ks=0; ks<4; ++ks){
        const float* p=&s_hid[row][ks*32+kg];
        float4 f0=*(const float4*)p, f1=*(const float4*)(p+4);
        float xs[8]={f0.x,f0.y,f0.z,f0.w,f1.x,f1.y,f1.z,f1.w};
        split8(xs,hhi[ks],hlo[ks]);
    }

    {
        f32x4 acc[8];
        #pragma unroll
        for (int nt2=0;nt2<8;++nt2){
            int col=(ch*8+nt2)*16+c15;
            float bv=(col<128)? b_in[col] : b_out[col-128];
            acc[nt2]=(f32x4){bv,bv,bv,bv};
        }
        #pragma unroll
        for (int ks=0; ks<4; ++ks){
            #pragma unroll
            for (int nt2=0; nt2<8; ++nt2){
                int nt=ch*8+nt2;
                size_t wo=((size_t)(nt*4+ks)*64+lane)*8;
                short8v bh=*(const short8v*)(wo_hi+wo);
                acc[nt2]=__builtin_amdgcn_mfma_f32_16x16x32_bf16(hhi[ks],bh,acc[nt2],0,0,0);
                acc[nt2]=__builtin_amdgcn_mfma_f32_16x16x32_bf16(hlo[ks],bh,acc[nt2],0,0,0);
            }
        }
        const int r0=g*4;
        #pragma unroll
        for (int nt2=0;nt2<8;++nt2){
            int col=(ch*8+nt2)*16+c15;
            short4v h4;
            #pragma unroll
            for (int j=0;j<4;++j) h4[j]=(short)bf16rn(acc[nt2][j]);
            *(short4v*)&U.hvT.hi[col][mi*16+r0] = h4;
        }
    }
    __syncthreads();

    f32x4 acc2[8];
    {
        #pragma unroll
        for (int nt2=0;nt2<8;++nt2){
            int col=(ch*8+nt2)*16+c15;
            float bv=(col<128)? b_iah[col] : b_oah[col-128];
            acc2[nt2]=(f32x4){bv,bv,bv,bv};
        }
        short8v ahi[2], alo[2];
        const float* Ab = Amat + (size_t)bl*8192 + (size_t)row*128 + (ch?64:0);
        #pragma unroll
        for (int ks=0;ks<2;++ks){
            float4 f0=*(const float4*)(Ab+ks*32+kg);
            float4 f1=*(const float4*)(Ab+ks*32+kg+4);
            float xs[8]={f0.x,f0.y,f0.z,f0.w,f1.x,f1.y,f1.z,f1.w};
            split8(xs,ahi[ks],alo[ks]);
        }
        #pragma unroll
        for (int ks=0;ks<2;++ks){
            #pragma unroll
            for (int nt2=0;nt2<8;++nt2){
                int h=(ch*8+nt2)*16+c15;
                int m0=ks*32+kg;
                short8v bh=*(const short8v*)&U.hvT.hi[h][m0];
                acc2[nt2]=__builtin_amdgcn_mfma_f32_16x16x32_bf16(ahi[ks],bh,acc2[nt2],0,0,0);
                acc2[nt2]=__builtin_amdgcn_mfma_f32_16x16x32_bf16(alo[ks],bh,acc2[nt2],0,0,0);
            }
        }
    }
    __syncthreads();

    {
        #pragma unroll
        for (int nt2=0;nt2<8;++nt2){
            int col=(ch*8+nt2)*16+c15;
            #pragma unroll
            for (int j=0;j<4;++j)
                U.inp[mi*16+g*4+j][col]=acc2[nt2][j];
        }
    }

    auto stage=[&](int ks, int buf){
        #pragma unroll
        for (int i=0;i<3;++i){
            int idx=i*512+t;
            int nt=idx>>6, ln=idx&63;
            const unsigned short *sh;
            if (ks<4){ sh = whh_hi + ((size_t)(nt*4+ks)*64+ln)*8; }
            else     { sh = wih_hi + ((size_t)(nt*8+(ks-4))*64+ln)*8; }
            *(short8v*)&wbuf[buf][nt][ln*8] = *(const short8v*)sh;
        }
    };

    f32x4 agi[12], agh[12];
    #pragma unroll
    for (int j=0;j<12;++j){
        int nt=(j>>2)*8 + ch*4 + (j&3);
        int col=nt*16+c15;
        float bi=b_ih[col], bh=b_hh[col];
        agi[j]=(f32x4){bi,bi,bi,bi};
        agh[j]=(f32x4){bh,bh,bh,bh};
    }

    stage(0,0);
    __syncthreads();
    for (int ks=0; ks<12; ++ks){
        int buf=ks&1;
        if (ks<11) stage(ks+1, buf^1);
        short8v ah, al;
        if (ks<4){
            ah=hhi[ks]; al=hlo[ks];
        } else {
            const float* p=&U.inp[row][(ks-4)*32+kg];
            float4 f0=*(const float4*)p, f1=*(const float4*)(p+4);
            float xs[8]={f0.x,f0.y,f0.z,f0.w,f1.x,f1.y,f1.z,f1.w};
            split8(xs,ah,al);
        }
        if (ks<4){
            #pragma unroll
            for (int j=0;j<12;++j){
                int nt=(j>>2)*8 + ch*4 + (j&3);
                short8v bh=*(const short8v*)&wbuf[buf][nt][lane*8];
                agh[j]=__builtin_amdgcn_mfma_f32_16x16x32_bf16(ah,bh,agh[j],0,0,0);
                agh[j]=__builtin_amdgcn_mfma_f32_16x16x32_bf16(al,bh,agh[j],0,0,0);
            }
        } else {
            #pragma unroll
            for (int j=0;j<12;++j){
                int nt=(j>>2)*8 + ch*4 + (j&3);
                short8v bh=*(const short8v*)&wbuf[buf][nt][lane*8];
                agi[j]=__builtin_amdgcn_mfma_f32_16x16x32_bf16(ah,bh,agi[j],0,0,0);
                agi[j]=__builtin_amdgcn_mfma_f32_16x16x32_bf16(al,bh,agi[j],0,0,0);
            }
        }
        __syncthreads();
    }

    const int r0=mi*16+g*4;
    #pragma unroll
    for (int sub=0;sub<4;++sub){
        int h=(ch*4+sub)*16+c15;
        #pragma unroll
        for (int j2=0;j2<4;++j2){
            float ir=agi[sub][j2], ii=agi[4+sub][j2], in_=agi[8+sub][j2];
            float hr=agh[sub][j2], hi_=agh[4+sub][j2], hn=agh[8+sub][j2];
            float rg=sigmoidf_(ir+hr), ig=sigmoidf_(ii+hi_);
            float ng=tanhf(in_+rg*hn);
            float ho=s_hid[r0+j2][h];
            hidnew[(size_t)(bl*64+r0+j2)*128+h]=ng+ig*(ho-ng);
        }
    }
}

// ---------------- fused tail: seq + q1/q2 + attention + afin -> pA frags ----------------
__global__ __launch_bounds__(256) void k_tail(
    const int* __restrict__ alias, const float* __restrict__ pos,
    const float* __restrict__ hn,
    const unsigned short* __restrict__ lp_hi, const unsigned short* __restrict__ lp_lo,
    const unsigned short* __restrict__ w2_hi, const unsigned short* __restrict__ w2_lo,
    const float* __restrict__ b2,
    const float* __restrict__ W1, const float* __restrict__ b1,
    const float* __restrict__ W3,
    const float* __restrict__ Wt, const float* __restrict__ bt,
    unsigned short* __restrict__ pA_hi, unsigned short* __restrict__ pA_lo)
{
    const int t=threadIdx.x, lane=t&63, w=t>>6, b=blockIdx.x;
    const int c15=lane&15, g=lane>>4;

    __shared__ union { float X[64][260]; float S[64][132]; } U;
    __shared__ int s_alias[64];
    __shared__ float s_q1[128], s_ht[128], s_alpha[64], s_a[128];
    __shared__ float s_pp[2][128];
    __shared__ int s_last;

    if (t<64) s_alias[t]=alias[b*64+t];
    __syncthreads();
    if (t==0){
        int c=0;
        for (int l=0;l<64;++l) c += (s_alias[l]>0) ? 1 : 0;
        s_last=(c-1)&63;
    }
    #pragma unroll
    for (int c=0;c<8;++c){
        int flat=c*1024+t*4, l=flat>>7, k=flat&127;
        *(float4*)&U.X[l][k] = *(const float4*)(pos + l*128 + k);
        int row=s_alias[l];
        *(float4*)&U.X[l][128+k] = *(const float4*)(hn + (size_t)(b*64 + row)*128 + k);
    }
    __syncthreads();

    f32x4 acc[8];
    #pragma unroll
    for (int nt=0;nt<8;++nt) acc[nt]=(f32x4){0.f,0.f,0.f,0.f};
    #pragma unroll
    for (int ks=0;ks<8;++ks){
        const float* xp=&U.X[w*16+c15][ks*32+g*8];
        float4 f0=*(const float4*)xp, f1=*(const float4*)(xp+4);
        float xs[8]={f0.x,f0.y,f0.z,f0.w,f1.x,f1.y,f1.z,f1.w};
        short8v ah,al; split8(xs,ah,al);
        #pragma unroll
        for (int nt=0;nt<8;++nt){
            size_t off=((size_t)(nt*8+ks)*64+lane)*8;
            short8v bh=*(const short8v*)(lp_hi+off);
            short8v bl_=*(const short8v*)(lp_lo+off);
            acc[nt]=__builtin_amdgcn_mfma_f32_16x16x32_bf16(ah,bh,acc[nt],0,0,0);
            acc[nt]=__builtin_amdgcn_mfma_f32_16x16x32_bf16(al,bh,acc[nt],0,0,0);
            acc[nt]=__builtin_amdgcn_mfma_f32_16x16x32_bf16(ah,bl_,acc[nt],0,0,0);
        }
    }
    float pj[4]={0.f,0.f,0.f,0.f};
    #pragma unroll
    for (int nt=0;nt<8;++nt){
        #pragma unroll
        for (int j=0;j<4;++j){
            float v=tanhf(acc[nt][j]);
            acc[nt][j]=v;
            pj[j]=fmaf(v,v,pj[j]);
        }
    }
    #pragma unroll
    for (int m=1;m<16;m<<=1){
        #pragma unroll
        for (int j=0;j<4;++j) pj[j]+=__shfl_xor(pj[j],m,64);
    }
    float rn[4];
    #pragma unroll
    for (int j=0;j<4;++j) rn[j]=rsqrtf(pj[j]);

    __syncthreads();
    #pragma unroll
    for (int nt=0;nt<8;++nt){
        #pragma unroll
        for (int j=0;j<4;++j)
            U.S[w*16+g*4+j][nt*16+c15]=acc[nt][j]*rn[j];
    }
    __syncthreads();

    if (t<128) s_ht[t]=U.S[s_last][t];
    __syncthreads();

    {
        int h=t&127, half=t>>7;
        float o=0.f;
        const float* wr=W1+(size_t)h*128+half*64;
        const float* hp=s_ht+half*64;
        #pragma unroll 8
        for (int k=0;k<64;k+=4){
            float4 wv=*(const float4*)(wr+k);
            o += hp[k]*wv.x + hp[k+1]*wv.y + hp[k+2]*wv.z + hp[k+3]*wv.w;
        }
        s_pp[half][h]=o;
    }
    __syncthreads();
    if (t<128) s_q1[t]=b1[t]+s_pp[0][t]+s_pp[1][t];

    f32x4 acc2[8];
    #pragma unroll
    for (int nt=0;nt<8;++nt){
        float bv=b2[nt*16+c15];
        acc2[nt]=(f32x4){bv,bv,bv,bv};
    }
    #pragma unroll
    for (int ks=0;ks<4;++ks){
        const float* sp=&U.S[w*16+c15][ks*32+g*8];
        float4 f0=*(const float4*)sp, f1=*(const float4*)(sp+4);
        float xs[8]={f0.x,f0.y,f0.z,f0.w,f1.x,f1.y,f1.z,f1.w};
        short8v ah,al; split8(xs,ah,al);
        #pragma unroll
        for (int nt=0;nt<8;++nt){
            size_t off=((size_t)(nt*4+ks)*64+lane)*8;
            short8v bh=*(const short8v*)(w2_hi+off);
            short8v bl_=*(const short8v*)(w2_lo+off);
            acc2[nt]=__builtin_amdgcn_mfma_f32_16x16x32_bf16(ah,bh,acc2[nt],0,0,0);
            acc2[nt]=__builtin_amdgcn_mfma_f32_16x16x32_bf16(al,bh,acc2[nt],0,0,0);
            acc2[nt]=__builtin_amdgcn_mfma_f32_16x16x32_bf16(ah,bl_,acc2[nt],0,0,0);
        }
    }
    __syncthreads();

    {
        float pa[4]={0.f,0.f,0.f,0.f};
        #pragma unroll
        for (int nt=0;nt<8;++nt){
            int col=nt*16+c15;
            float w3v=W3[col];
            #pragma unroll
            for (int j=0;j<4;++j)
                pa[j]=fmaf(sigmoidf_(s_q1[col]+acc2[nt][j]), w3v, pa[j]);
        }
        #pragma unroll
        for (int m=1;m<16;m<<=1){
            #pragma unroll
            for (int j=0;j<4;++j) pa[j]+=__shfl_xor(pa[j],m,64);
        }
        if (c15==0){
            #pragma unroll
            for (int j=0;j<4;++j){
                int l=w*16+g*4+j;
                s_alpha[l]=(s_alias[l]>0)? pa[j] : 0.f;
            }
        }
    }
    __syncthreads();

    {
        int h=t&127, half=t>>7;
        float a_=0.f;
        #pragma unroll 8
        for (int l=half*32;l<half*32+32;++l) a_=fmaf(s_alpha[l],U.S[l][h],a_);
        s_pp[half][h]=a_;
    }
    __syncthreads();
    if (t<128) s_a[t]=s_pp[0][t]+s_pp[1][t];
    __syncthreads();

    {
        int h=t&127, half=t>>7;
        float o=0.f;
        const float* wr=Wt+(size_t)h*256+half*128;
        const float* vp=(half==0)? s_a : s_ht;
        #pragma unroll 8
        for (int k=0;k<128;k+=4){
            float4 wv=*(const float4*)(wr+k);
            o += vp[k]*wv.x + vp[k+1]*wv.y + vp[k+2]*wv.z + vp[k+3]*wv.w;
        }
        s_pp[half][h]=o;
    }
    __syncthreads();
    if (t<128){
        float o=bt[t]+s_pp[0][t]+s_pp[1][t];
        unsigned short hi,lo; split_bf16(o,hi,lo);
        int mt=b>>4, r15=b&15;
        int ks=t>>5, gg=(t>>3)&3, e=t&7;
        int lz=gg*16+r15;
        size_t off=(((size_t)mt*4+ks)*64+lz)*8+e;
        pA_hi[off]=hi; pA_lo[off]=lo;
    }
}

// ---------------- pred v4: inline emb conversion, (391,2) grid for load balance ----------------
__global__ __launch_bounds__(512,1) void k_pred_mfma(
    const unsigned short* __restrict__ Ahi, const unsigned short* __restrict__ Alo,
    const float* __restrict__ emb, float* __restrict__ outp)
{
    const int t=threadIdx.x, lane=t&63, w=t>>6;
    const int st=blockIdx.x;
    const int c15=lane&15, g=lane>>4;

    __shared__ unsigned short Bsh[32768];
    __shared__ float S[8][8][264];

    #pragma unroll
    for (int p=0;p<16;++p){
        int c = p*512 + t;
        int r = c>>5, k0 = (c&31)*4;
        int v = st*256 + r;
        int srcr = (v < NVOCAB) ? (v+1) : 0;
        float4 f = *(const float4*)(emb + (size_t)srcr*128 + k0);
        int q_s = (r>>6)*16 + ((r>>4)&3)*4 + (k0>>5);
        int ln  = ((k0>>3)&3)*16 + (r&15);
        short4v h4;
        h4[0]=(short)bf16rn(f.x); h4[1]=(short)bf16rn(f.y);
        h4[2]=(short)bf16rn(f.z); h4[3]=(short)bf16rn(f.w);
        *(short4v*)&Bsh[(q_s*64+ln)*8 + (k0&7)] = h4;
    }
    __syncthreads();

    for (int rg2=0; rg2<2; ++rg2){
        const int rg = blockIdx.y*2 + rg2;
        const int mt = rg*8 + w;
        short8v ahi[4], alo[4];
        #pragma unroll
        for (int ks=0;ks<4;++ks){
            size_t off=((size_t)(mt*4+ks)*64+lane)*8;
            ahi[ks]=*(const short8v*)(Ahi+off);
            alo[ks]=*(const short8v*)(Alo+off);
        }

        f32x4 acc[16];
        __builtin_amdgcn_s_setprio(1);
        #pragma unroll
        for (int ntl=0;ntl<16;++ntl){
            acc[ntl]=(f32x4){0.f,0.f,0.f,0.f};
            #pragma unroll
            for (int ks=0;ks<4;++ks){
                short8v bh = *(const short8v*)&Bsh[(size_t)((ntl*4+ks)*64 + lane)*8];
                acc[ntl]=__builtin_amdgcn_mfma_f32_16x16x32_bf16(ahi[ks],bh,acc[ntl],0,0,0);
                acc[ntl]=__builtin_amdgcn_mfma_f32_16x16x32_bf16(alo[ks],bh,acc[ntl],0,0,0);
            }
        }
        __builtin_amdgcn_s_setprio(0);

        #pragma unroll
        for (int hh=0; hh<2; ++hh){
            if ((g>>1) == hh){
                int rloc=(g&1)*4;
                #pragma unroll
                for (int ntl=0;ntl<16;++ntl){
                    #pragma unroll
                    for (int j=0;j<4;++j)
                        S[w][rloc+j][ntl*16+c15] = 16.0f*acc[ntl][j];
                }
            }
            __syncthreads();
            #pragma unroll
            for (int p=0;p<8;++p){
                int row = mt*16 + hh*8 + p;
                int col0 = st*256 + lane*4;
                f32x4 o = *(f32x4*)&S[w][p][lane*4];
                size_t rowoff = (size_t)row*NVOCAB;
                if (col0 + 3 < NVOCAB){
                    __builtin_nontemporal_store(o, (f32x4*)(outp + rowoff + col0));
                } else {
                    #pragma unroll
                    for (int cc2=0;cc2<4;++cc2)
                        if (col0+cc2 < NVOCAB) outp[rowoff + col0 + cc2] = o[cc2];
                }
            }
            __syncthreads();
        }
    }
}

extern "C" void kernel_launch(void* const* d_in, const int* in_sizes, int n_in,
                              void* d_out, int out_size, void* d_ws, size_t ws_size,
                              hipStream_t stream)
{
    const int*   items = (const int*)  d_in[0];
    const float* Amat  = (const float*)d_in[1];
    const int*   alias = (const int*)  d_in[2];
    const float* emb   = (const float*)d_in[3];
    const float* pos   = (const float*)d_in[4];
    const float* lp    = (const float*)d_in[5];
    const float* w_ih  = (const float*)d_in[6];
    const float* w_hh  = (const float*)d_in[7];
    const float* b_ih  = (const float*)d_in[8];
    const float* b_hh  = (const float*)d_in[9];
    const float* b_iah = (const float*)d_in[10];
    const float* b_oah = (const float*)d_in[11];
    const float* W_in  = (const float*)d_in[12];
    const float* b_in  = (const float*)d_in[13];
    const float* W_out = (const float*)d_in[14];
    const float* b_out = (const float*)d_in[15];
    const float* W1    = (const float*)d_in[16];
    const float* b1    = (const float*)d_in[17];
    const float* W2    = (const float*)d_in[18];
    const float* b2    = (const float*)d_in[19];
    const float* W3    = (const float*)d_in[20];
    const float* Wt    = (const float*)d_in[21];
    const float* bt    = (const float*)d_in[22];
    float* outp = (float*)d_out;

    // ---- workspace carve ----
    float* wsf = (float*)d_ws;
    size_t o = 0;
    float* hidnew = wsf + o;               o += 4194304;
    unsigned short* us = (unsigned short*)(wsf + o);
    size_t uo = 0;
    unsigned short* wo_hi  = us + uo; uo += 32768;
    unsigned short* wih_hi = us + uo; uo += 98304;
    unsigned short* whh_hi = us + uo; uo += 49152;
    unsigned short* lp_hi  = us + uo; uo += 32768;
    unsigned short* lp_lo  = us + uo; uo += 32768;
    unsigned short* w2_hi  = us + uo; uo += 16384;
    unsigned short* w2_lo  = us + uo; uo += 16384;
    unsigned short* pA_hi  = us + uo; uo += 65536;
    unsigned short* pA_lo  = us + uo; uo += 65536;

    k_prep_wfrag<<<112, 256, 0, stream>>>(W_in, W_out, w_ih, w_hh, lp, W2,
                                          wo_hi, wih_hi, whh_hi,
                                          lp_hi, lp_lo, w2_hi, w2_lo);
    k_gnn<<<512, 512, 0, stream>>>(items, Amat, emb, b_in, b_out, b_iah, b_oah,
                                   wo_hi, wih_hi, whh_hi, b_ih, b_hh, hidnew);
    k_tail<<<512, 256, 0, stream>>>(alias, pos, hidnew,
                                    lp_hi, lp_lo, w2_hi, w2_lo, b2,
                                    W1, b1, W3, Wt, bt, pA_hi, pA_lo);
    k_pred_mfma<<<dim3(391, 2), 512, 0, stream>>>(pA_hi, pA_lo, emb, outp);
}

// Round 14
// 174.722 us; speedup vs baseline: 1.0405x; 1.0405x over previous
//
#include <hip/hip_runtime.h>
#include <cstddef>
#include <cstdint>

#define NVOCAB 99999

typedef __attribute__((ext_vector_type(8))) short short8v;
typedef __attribute__((ext_vector_type(4))) short short4v;
typedef __attribute__((ext_vector_type(4))) float f32x4;

__device__ __forceinline__ float sigmoidf_(float x){ return 1.0f/(1.0f + __expf(-x)); }

__device__ __forceinline__ unsigned short bf16rn(float x){
    union { float f; uint32_t u; } v; v.f = x;
    uint32_t r = v.u + 0x7FFFu + ((v.u >> 16) & 1u);
    return (unsigned short)(r >> 16);
}

__device__ __forceinline__ void split_bf16(float x, unsigned short &hi, unsigned short &lo){
    hi = bf16rn(x);
    union { uint32_t u; float f; } hf; hf.u = ((uint32_t)hi) << 16;
    lo = bf16rn(x - hf.f);
}

__device__ __forceinline__ void split8(const float* xs, short8v &h, short8v &l){
    #pragma unroll
    for (int e = 0; e < 8; ++e){
        unsigned short uh, ul;
        split_bf16(xs[e], uh, ul);
        h[e] = (short)uh; l[e] = (short)ul;
    }
}

// ---------------- prep: split weights into B-fragment layout ----------------
__global__ __launch_bounds__(256) void k_prep_wfrag(
    const float* __restrict__ W_in, const float* __restrict__ W_out,
    const float* __restrict__ w_ih, const float* __restrict__ w_hh,
    const float* __restrict__ lp,  const float* __restrict__ W2,
    unsigned short* __restrict__ wo_hi,
    unsigned short* __restrict__ wih_hi,
    unsigned short* __restrict__ whh_hi,
    unsigned short* __restrict__ lp_hi,  unsigned short* __restrict__ lp_lo,
    unsigned short* __restrict__ w2_hi,  unsigned short* __restrict__ w2_lo)
{
    int id = blockIdx.x*256 + threadIdx.x;
    if (id < 4096){
        int lane=id&63, tile=id>>6, nt=tile>>2, ks=tile&3;
        int col=nt*16+(lane&15), k=ks*32+(lane>>4)*8;
        const float* src = (col<128) ? (W_in + (size_t)col*128 + k) : (W_out + (size_t)(col-128)*128 + k);
        float4 f0=*(const float4*)src, f1=*(const float4*)(src+4);
        float xs[8]={f0.x,f0.y,f0.z,f0.w,f1.x,f1.y,f1.z,f1.w};
        short8v h;
        #pragma unroll
        for (int e=0;e<8;++e) h[e]=(short)bf16rn(xs[e]);
        *(short8v*)(wo_hi+(size_t)id*8)=h;
    } else if (id < 16384){
        int t2=id-4096, lane=t2&63, tile=t2>>6, nt=tile>>3, ks=tile&7;
        int col=nt*16+(lane&15), k=ks*32+(lane>>4)*8;
        const float* src = w_ih + (size_t)col*256 + k;
        float4 f0=*(const float4*)src, f1=*(const float4*)(src+4);
        short8v h;
        float xs[8]={f0.x,f0.y,f0.z,f0.w,f1.x,f1.y,f1.z,f1.w};
        #pragma unroll
        for (int e=0;e<8;++e) h[e]=(short)bf16rn(xs[e]);
        *(short8v*)(wih_hi+(size_t)t2*8)=h;
    } else if (id < 22528){
        int t3=id-16384, lane=t3&63, tile=t3>>6, nt=tile>>2, ks=tile&3;
        int col=nt*16+(lane&15), k=ks*32+(lane>>4)*8;
        const float* src = w_hh + (size_t)col*128 + k;
        float4 f0=*(const float4*)src, f1=*(const float4*)(src+4);
        short8v h;
        float xs[8]={f0.x,f0.y,f0.z,f0.w,f1.x,f1.y,f1.z,f1.w};
        #pragma unroll
        for (int e=0;e<8;++e) h[e]=(short)bf16rn(xs[e]);
        *(short8v*)(whh_hi+(size_t)t3*8)=h;
    } else if (id < 26624){
        int t4=id-22528, lane=t4&63, tile=t4>>6, nt=tile>>3, ks=tile&7;
        int col=nt*16+(lane&15), k=ks*32+(lane>>4)*8;
        float xs[8];
        #pragma unroll
        for (int e=0;e<8;++e) xs[e]=lp[(size_t)(k+e)*128 + col];
        short8v h,l; split8(xs,h,l);
        *(short8v*)(lp_hi+(size_t)t4*8)=h; *(short8v*)(lp_lo+(size_t)t4*8)=l;
    } else if (id < 28672){
        int t5=id-26624, lane=t5&63, tile=t5>>6, nt=tile>>2, ks=tile&3;
        int col=nt*16+(lane&15), k=ks*32+(lane>>4)*8;
        const float* src = W2 + (size_t)col*128 + k;
        float4 f0=*(const float4*)src, f1=*(const float4*)(src+4);
        float xs[8]={f0.x,f0.y,f0.z,f0.w,f1.x,f1.y,f1.z,f1.w};
        short8v h,l; split8(xs,h,l);
        *(short8v*)(w2_hi+(size_t)t5*8)=h; *(short8v*)(w2_lo+(size_t)t5*8)=l;
    }
}

// ---------------- fused GNN: gather + hv + bmm + gi/gh GEMM + GRU gate -> hidnew ----------------
union SharedU {
    struct { unsigned short hi[256][72]; } hvT;  // 36864 B (hi-only)
    float inp[64][268];                          // 68608 B
};

__global__ __launch_bounds__(512,1) void k_gnn(
    const int* __restrict__ items, const float* __restrict__ Amat,
    const float* __restrict__ emb,
    const float* __restrict__ b_in, const float* __restrict__ b_out,
    const float* __restrict__ b_iah, const float* __restrict__ b_oah,
    const unsigned short* __restrict__ wo_hi,
    const unsigned short* __restrict__ wih_hi, const unsigned short* __restrict__ whh_hi,
    const float* __restrict__ b_ih, const float* __restrict__ b_hh,
    float* __restrict__ hidnew)
{
    const int t=threadIdx.x, lane=t&63, w=t>>6, bl=blockIdx.x;
    const int mi=w&3, ch=w>>2;
    const int c15=lane&15, g=lane>>4, kg=g*8;
    const int row=mi*16+c15;

    __shared__ int s_items[64];
    __shared__ float s_hid[64][132];
    __shared__ SharedU U;

    if (t < 64) s_items[t]=items[bl*64+t];
    __syncthreads();

    // ---- phase 1: gather emb -> s_hid ----
    {
        int r=t>>3, c0=(t&7)*16;
        const float* src = emb + (size_t)s_items[r]*128 + c0;
        float4 v0=*(const float4*)(src);
        float4 v1=*(const float4*)(src+4);
        float4 v2=*(const float4*)(src+8);
        float4 v3=*(const float4*)(src+12);
        *(float4*)&s_hid[r][c0]   = v0;
        *(float4*)&s_hid[r][c0+4] = v1;
        *(float4*)&s_hid[r][c0+8] = v2;
        *(float4*)&s_hid[r][c0+12]= v3;
    }
    __syncthreads();

    short8v hhi[4], hlo[4];
    #pragma unroll
    for (int ks=0; ks<4; ++ks){
        const float* p=&s_hid[row][ks*32+kg];
        float4 f0=*(const float4*)p, f1=*(const float4*)(p+4);
        float xs[8]={f0.x,f0.y,f0.z,f0.w,f1.x,f1.y,f1.z,f1.w};
        split8(xs,hhi[ks],hlo[ks]);
    }

    // ---- phase 2: hv = hidden @ [W_in^T|W_out^T] + bias ----
    {
        f32x4 acc[8];
        #pragma unroll
        for (int nt2=0;nt2<8;++nt2){
            int col=(ch*8+nt2)*16+c15;
            float bv=(col<128)? b_in[col] : b_out[col-128];
            acc[nt2]=(f32x4){bv,bv,bv,bv};
        }
        #pragma unroll
        for (int ks=0; ks<4; ++ks){
            #pragma unroll
            for (int nt2=0; nt2<8; ++nt2){
                int nt=ch*8+nt2;
                size_t wo=((size_t)(nt*4+ks)*64+lane)*8;
                short8v bh=*(const short8v*)(wo_hi+wo);
                acc[nt2]=__builtin_amdgcn_mfma_f32_16x16x32_bf16(hhi[ks],bh,acc[nt2],0,0,0);
                acc[nt2]=__builtin_amdgcn_mfma_f32_16x16x32_bf16(hlo[ks],bh,acc[nt2],0,0,0);
            }
        }
        const int r0=g*4;
        #pragma unroll
        for (int nt2=0;nt2<8;++nt2){
            int col=(ch*8+nt2)*16+c15;
            short4v h4;
            #pragma unroll
            for (int j=0;j<4;++j) h4[j]=(short)bf16rn(acc[nt2][j]);
            *(short4v*)&U.hvT.hi[col][mi*16+r0] = h4;
        }
    }
    __syncthreads();

    // ---- phase 3: bmm inputs = A @ hv + bias ----
    f32x4 acc2[8];
    {
        #pragma unroll
        for (int nt2=0;nt2<8;++nt2){
            int col=(ch*8+nt2)*16+c15;
            float bv=(col<128)? b_iah[col] : b_oah[col-128];
            acc2[nt2]=(f32x4){bv,bv,bv,bv};
        }
        short8v ahi[2], alo[2];
        const float* Ab = Amat + (size_t)bl*8192 + (size_t)row*128 + (ch?64:0);
        #pragma unroll
        for (int ks=0;ks<2;++ks){
            float4 f0=*(const float4*)(Ab+ks*32+kg);
            float4 f1=*(const float4*)(Ab+ks*32+kg+4);
            float xs[8]={f0.x,f0.y,f0.z,f0.w,f1.x,f1.y,f1.z,f1.w};
            split8(xs,ahi[ks],alo[ks]);
        }
        #pragma unroll
        for (int ks=0;ks<2;++ks){
            #pragma unroll
            for (int nt2=0;nt2<8;++nt2){
                int h=(ch*8+nt2)*16+c15;
                int m0=ks*32+kg;
                short8v bh=*(const short8v*)&U.hvT.hi[h][m0];
                acc2[nt2]=__builtin_amdgcn_mfma_f32_16x16x32_bf16(ahi[ks],bh,acc2[nt2],0,0,0);
                acc2[nt2]=__builtin_amdgcn_mfma_f32_16x16x32_bf16(alo[ks],bh,acc2[nt2],0,0,0);
            }
        }
    }
    __syncthreads();   // done reading hvT (union reuse below)

    // ---- phase 4: inputs f32 -> LDS ----
    {
        #pragma unroll
        for (int nt2=0;nt2<8;++nt2){
            int col=(ch*8+nt2)*16+c15;
            #pragma unroll
            for (int j=0;j<4;++j)
                U.inp[mi*16+g*4+j][col]=acc2[nt2][j];
        }
    }
    __syncthreads();   // inp visible to all; no further barriers needed

    // ---- phase 5: gi/gh GEMM, weights streamed straight from L2 (no LDS, no barriers) ----
    f32x4 agi[12], agh[12];
    #pragma unroll
    for (int j=0;j<12;++j){
        int nt=(j>>2)*8 + ch*4 + (j&3);
        int col=nt*16+c15;
        float bi=b_ih[col], bh=b_hh[col];
        agi[j]=(f32x4){bi,bi,bi,bi};
        agh[j]=(f32x4){bh,bh,bh,bh};
    }

    #pragma unroll
    for (int ks=0; ks<4; ++ks){
        #pragma unroll
        for (int j=0;j<12;++j){
            int nt=(j>>2)*8 + ch*4 + (j&3);
            short8v bh=*(const short8v*)(whh_hi + ((size_t)(nt*4+ks)*64+lane)*8);
            agh[j]=__builtin_amdgcn_mfma_f32_16x16x32_bf16(hhi[ks],bh,agh[j],0,0,0);
            agh[j]=__builtin_amdgcn_mfma_f32_16x16x32_bf16(hlo[ks],bh,agh[j],0,0,0);
        }
    }
    #pragma unroll
    for (int ks=0; ks<8; ++ks){
        const float* p=&U.inp[row][ks*32+kg];
        float4 f0=*(const float4*)p, f1=*(const float4*)(p+4);
        float xs[8]={f0.x,f0.y,f0.z,f0.w,f1.x,f1.y,f1.z,f1.w};
        short8v ah,al; split8(xs,ah,al);
        #pragma unroll
        for (int j=0;j<12;++j){
            int nt=(j>>2)*8 + ch*4 + (j&3);
            short8v bh=*(const short8v*)(wih_hi + ((size_t)(nt*8+ks)*64+lane)*8);
            agi[j]=__builtin_amdgcn_mfma_f32_16x16x32_bf16(ah,bh,agi[j],0,0,0);
            agi[j]=__builtin_amdgcn_mfma_f32_16x16x32_bf16(al,bh,agi[j],0,0,0);
        }
    }

    // ---- phase 6: fused GRU gate -> hidnew ----
    const int r0=mi*16+g*4;
    #pragma unroll
    for (int sub=0;sub<4;++sub){
        int h=(ch*4+sub)*16+c15;
        #pragma unroll
        for (int j2=0;j2<4;++j2){
            float ir=agi[sub][j2], ii=agi[4+sub][j2], in_=agi[8+sub][j2];
            float hr=agh[sub][j2], hi_=agh[4+sub][j2], hn=agh[8+sub][j2];
            float rg=sigmoidf_(ir+hr), ig=sigmoidf_(ii+hi_);
            float ng=tanhf(in_+rg*hn);
            float ho=s_hid[r0+j2][h];
            hidnew[(size_t)(bl*64+r0+j2)*128+h]=ng+ig*(ho-ng);
        }
    }
}

// ---------------- fused tail: seq + q1/q2 + attention + afin -> pA frags ----------------
__global__ __launch_bounds__(256) void k_tail(
    const int* __restrict__ alias, const float* __restrict__ pos,
    const float* __restrict__ hn,
    const unsigned short* __restrict__ lp_hi, const unsigned short* __restrict__ lp_lo,
    const unsigned short* __restrict__ w2_hi, const unsigned short* __restrict__ w2_lo,
    const float* __restrict__ b2,
    const float* __restrict__ W1, const float* __restrict__ b1,
    const float* __restrict__ W3,
    const float* __restrict__ Wt, const float* __restrict__ bt,
    unsigned short* __restrict__ pA_hi, unsigned short* __restrict__ pA_lo)
{
    const int t=threadIdx.x, lane=t&63, w=t>>6, b=blockIdx.x;
    const int c15=lane&15, g=lane>>4;

    __shared__ union { float X[64][260]; float S[64][132]; } U;
    __shared__ int s_alias[64];
    __shared__ float s_q1[128], s_ht[128], s_alpha[64], s_a[128];
    __shared__ float s_pp[2][128];
    __shared__ int s_last;

    if (t<64) s_alias[t]=alias[b*64+t];
    __syncthreads();
    if (t==0){
        int c=0;
        for (int l=0;l<64;++l) c += (s_alias[l]>0) ? 1 : 0;
        s_last=(c-1)&63;
    }
    #pragma unroll
    for (int c=0;c<8;++c){
        int flat=c*1024+t*4, l=flat>>7, k=flat&127;
        *(float4*)&U.X[l][k] = *(const float4*)(pos + l*128 + k);
        int row=s_alias[l];
        *(float4*)&U.X[l][128+k] = *(const float4*)(hn + (size_t)(b*64 + row)*128 + k);
    }
    __syncthreads();

    f32x4 acc[8];
    #pragma unroll
    for (int nt=0;nt<8;++nt) acc[nt]=(f32x4){0.f,0.f,0.f,0.f};
    #pragma unroll
    for (int ks=0;ks<8;++ks){
        const float* xp=&U.X[w*16+c15][ks*32+g*8];
        float4 f0=*(const float4*)xp, f1=*(const float4*)(xp+4);
        float xs[8]={f0.x,f0.y,f0.z,f0.w,f1.x,f1.y,f1.z,f1.w};
        short8v ah,al; split8(xs,ah,al);
        #pragma unroll
        for (int nt=0;nt<8;++nt){
            size_t off=((size_t)(nt*8+ks)*64+lane)*8;
            short8v bh=*(const short8v*)(lp_hi+off);
            short8v bl_=*(const short8v*)(lp_lo+off);
            acc[nt]=__builtin_amdgcn_mfma_f32_16x16x32_bf16(ah,bh,acc[nt],0,0,0);
            acc[nt]=__builtin_amdgcn_mfma_f32_16x16x32_bf16(al,bh,acc[nt],0,0,0);
            acc[nt]=__builtin_amdgcn_mfma_f32_16x16x32_bf16(ah,bl_,acc[nt],0,0,0);
        }
    }
    float pj[4]={0.f,0.f,0.f,0.f};
    #pragma unroll
    for (int nt=0;nt<8;++nt){
        #pragma unroll
        for (int j=0;j<4;++j){
            float v=tanhf(acc[nt][j]);
            acc[nt][j]=v;
            pj[j]=fmaf(v,v,pj[j]);
        }
    }
    #pragma unroll
    for (int m=1;m<16;m<<=1){
        #pragma unroll
        for (int j=0;j<4;++j) pj[j]+=__shfl_xor(pj[j],m,64);
    }
    float rn[4];
    #pragma unroll
    for (int j=0;j<4;++j) rn[j]=rsqrtf(pj[j]);

    __syncthreads();
    #pragma unroll
    for (int nt=0;nt<8;++nt){
        #pragma unroll
        for (int j=0;j<4;++j)
            U.S[w*16+g*4+j][nt*16+c15]=acc[nt][j]*rn[j];
    }
    __syncthreads();

    if (t<128) s_ht[t]=U.S[s_last][t];
    __syncthreads();

    {
        int h=t&127, half=t>>7;
        float o=0.f;
        const float* wr=W1+(size_t)h*128+half*64;
        const float* hp=s_ht+half*64;
        #pragma unroll 8
        for (int k=0;k<64;k+=4){
            float4 wv=*(const float4*)(wr+k);
            o += hp[k]*wv.x + hp[k+1]*wv.y + hp[k+2]*wv.z + hp[k+3]*wv.w;
        }
        s_pp[half][h]=o;
    }
    __syncthreads();
    if (t<128) s_q1[t]=b1[t]+s_pp[0][t]+s_pp[1][t];

    f32x4 acc2[8];
    #pragma unroll
    for (int nt=0;nt<8;++nt){
        float bv=b2[nt*16+c15];
        acc2[nt]=(f32x4){bv,bv,bv,bv};
    }
    #pragma unroll
    for (int ks=0;ks<4;++ks){
        const float* sp=&U.S[w*16+c15][ks*32+g*8];
        float4 f0=*(const float4*)sp, f1=*(const float4*)(sp+4);
        float xs[8]={f0.x,f0.y,f0.z,f0.w,f1.x,f1.y,f1.z,f1.w};
        short8v ah,al; split8(xs,ah,al);
        #pragma unroll
        for (int nt=0;nt<8;++nt){
            size_t off=((size_t)(nt*4+ks)*64+lane)*8;
            short8v bh=*(const short8v*)(w2_hi+off);
            short8v bl_=*(const short8v*)(w2_lo+off);
            acc2[nt]=__builtin_amdgcn_mfma_f32_16x16x32_bf16(ah,bh,acc2[nt],0,0,0);
            acc2[nt]=__builtin_amdgcn_mfma_f32_16x16x32_bf16(al,bh,acc2[nt],0,0,0);
            acc2[nt]=__builtin_amdgcn_mfma_f32_16x16x32_bf16(ah,bl_,acc2[nt],0,0,0);
        }
    }
    __syncthreads();

    {
        float pa[4]={0.f,0.f,0.f,0.f};
        #pragma unroll
        for (int nt=0;nt<8;++nt){
            int col=nt*16+c15;
            float w3v=W3[col];
            #pragma unroll
            for (int j=0;j<4;++j)
                pa[j]=fmaf(sigmoidf_(s_q1[col]+acc2[nt][j]), w3v, pa[j]);
        }
        #pragma unroll
        for (int m=1;m<16;m<<=1){
            #pragma unroll
            for (int j=0;j<4;++j) pa[j]+=__shfl_xor(pa[j],m,64);
        }
        if (c15==0){
            #pragma unroll
            for (int j=0;j<4;++j){
                int l=w*16+g*4+j;
                s_alpha[l]=(s_alias[l]>0)? pa[j] : 0.f;
            }
        }
    }
    __syncthreads();

    {
        int h=t&127, half=t>>7;
        float a_=0.f;
        #pragma unroll 8
        for (int l=half*32;l<half*32+32;++l) a_=fmaf(s_alpha[l],U.S[l][h],a_);
        s_pp[half][h]=a_;
    }
    __syncthreads();
    if (t<128) s_a[t]=s_pp[0][t]+s_pp[1][t];
    __syncthreads();

    {
        int h=t&127, half=t>>7;
        float o=0.f;
        const float* wr=Wt+(size_t)h*256+half*128;
        const float* vp=(half==0)? s_a : s_ht;
        #pragma unroll 8
        for (int k=0;k<128;k+=4){
            float4 wv=*(const float4*)(wr+k);
            o += vp[k]*wv.x + vp[k+1]*wv.y + vp[k+2]*wv.z + vp[k+3]*wv.w;
        }
        s_pp[half][h]=o;
    }
    __syncthreads();
    if (t<128){
        float o=bt[t]+s_pp[0][t]+s_pp[1][t];
        unsigned short hi,lo; split_bf16(o,hi,lo);
        int mt=b>>4, r15=b&15;
        int ks=t>>5, gg=(t>>3)&3, e=t&7;
        int lz=gg*16+r15;
        size_t off=(((size_t)mt*4+ks)*64+lz)*8+e;
        pA_hi[off]=hi; pA_lo[off]=lo;
    }
}

// ---------------- pred v3 (R11 config): inline emb conversion, 391 blocks, rg 0..3 ----------------
__global__ __launch_bounds__(512,1) void k_pred_mfma(
    const unsigned short* __restrict__ Ahi, const unsigned short* __restrict__ Alo,
    const float* __restrict__ emb, float* __restrict__ outp)
{
    const int t=threadIdx.x, lane=t&63, w=t>>6;
    const int st=blockIdx.x;
    const int c15=lane&15, g=lane>>4;

    __shared__ unsigned short Bsh[32768];
    __shared__ float S[8][8][264];

    #pragma unroll
    for (int p=0;p<16;++p){
        int c = p*512 + t;
        int r = c>>5, k0 = (c&31)*4;
        int v = st*256 + r;
        int srcr = (v < NVOCAB) ? (v+1) : 0;
        float4 f = *(const float4*)(emb + (size_t)srcr*128 + k0);
        int q_s = (r>>6)*16 + ((r>>4)&3)*4 + (k0>>5);
        int ln  = ((k0>>3)&3)*16 + (r&15);
        short4v h4;
        h4[0]=(short)bf16rn(f.x); h4[1]=(short)bf16rn(f.y);
        h4[2]=(short)bf16rn(f.z); h4[3]=(short)bf16rn(f.w);
        *(short4v*)&Bsh[(q_s*64+ln)*8 + (k0&7)] = h4;
    }
    __syncthreads();

    for (int rg=0; rg<4; ++rg){
        const int mt = rg*8 + w;
        short8v ahi[4], alo[4];
        #pragma unroll
        for (int ks=0;ks<4;++ks){
            size_t off=((size_t)(mt*4+ks)*64+lane)*8;
            ahi[ks]=*(const short8v*)(Ahi+off);
            alo[ks]=*(const short8v*)(Alo+off);
        }

        f32x4 acc[16];
        __builtin_amdgcn_s_setprio(1);
        #pragma unroll
        for (int ntl=0;ntl<16;++ntl){
            acc[ntl]=(f32x4){0.f,0.f,0.f,0.f};
            #pragma unroll
            for (int ks=0;ks<4;++ks){
                short8v bh = *(const short8v*)&Bsh[(size_t)((ntl*4+ks)*64 + lane)*8];
                acc[ntl]=__builtin_amdgcn_mfma_f32_16x16x32_bf16(ahi[ks],bh,acc[ntl],0,0,0);
                acc[ntl]=__builtin_amdgcn_mfma_f32_16x16x32_bf16(alo[ks],bh,acc[ntl],0,0,0);
            }
        }
        __builtin_amdgcn_s_setprio(0);

        #pragma unroll
        for (int hh=0; hh<2; ++hh){
            if ((g>>1) == hh){
                int rloc=(g&1)*4;
                #pragma unroll
                for (int ntl=0;ntl<16;++ntl){
                    #pragma unroll
                    for (int j=0;j<4;++j)
                        S[w][rloc+j][ntl*16+c15] = 16.0f*acc[ntl][j];
                }
            }
            __syncthreads();
            #pragma unroll
            for (int p=0;p<8;++p){
                int row = mt*16 + hh*8 + p;
                int col0 = st*256 + lane*4;
                f32x4 o = *(f32x4*)&S[w][p][lane*4];
                size_t rowoff = (size_t)row*NVOCAB;
                if (col0 + 3 < NVOCAB){
                    __builtin_nontemporal_store(o, (f32x4*)(outp + rowoff + col0));
                } else {
                    #pragma unroll
                    for (int cc2=0;cc2<4;++cc2)
                        if (col0+cc2 < NVOCAB) outp[rowoff + col0 + cc2] = o[cc2];
                }
            }
            __syncthreads();
        }
    }
}

extern "C" void kernel_launch(void* const* d_in, const int* in_sizes, int n_in,
                              void* d_out, int out_size, void* d_ws, size_t ws_size,
                              hipStream_t stream)
{
    const int*   items = (const int*)  d_in[0];
    const float* Amat  = (const float*)d_in[1];
    const int*   alias = (const int*)  d_in[2];
    const float* emb   = (const float*)d_in[3];
    const float* pos   = (const float*)d_in[4];
    const float* lp    = (const float*)d_in[5];
    const float* w_ih  = (const float*)d_in[6];
    const float* w_hh  = (const float*)d_in[7];
    const float* b_ih  = (const float*)d_in[8];
    const float* b_hh  = (const float*)d_in[9];
    const float* b_iah = (const float*)d_in[10];
    const float* b_oah = (const float*)d_in[11];
    const float* W_in  = (const float*)d_in[12];
    const float* b_in  = (const float*)d_in[13];
    const float* W_out = (const float*)d_in[14];
    const float* b_out = (const float*)d_in[15];
    const float* W1    = (const float*)d_in[16];
    const float* b1    = (const float*)d_in[17];
    const float* W2    = (const float*)d_in[18];
    const float* b2    = (const float*)d_in[19];
    const float* W3    = (const float*)d_in[20];
    const float* Wt    = (const float*)d_in[21];
    const float* bt    = (const float*)d_in[22];
    float* outp = (float*)d_out;

    // ---- workspace carve ----
    float* wsf = (float*)d_ws;
    size_t o = 0;
    float* hidnew = wsf + o;               o += 4194304;
    unsigned short* us = (unsigned short*)(wsf + o);
    size_t uo = 0;
    unsigned short* wo_hi  = us + uo; uo += 32768;
    unsigned short* wih_hi = us + uo; uo += 98304;
    unsigned short* whh_hi = us + uo; uo += 49152;
    unsigned short* lp_hi  = us + uo; uo += 32768;
    unsigned short* lp_lo  = us + uo; uo += 32768;
    unsigned short* w2_hi  = us + uo; uo += 16384;
    unsigned short* w2_lo  = us + uo; uo += 16384;
    unsigned short* pA_hi  = us + uo; uo += 65536;
    unsigned short* pA_lo  = us + uo; uo += 65536;

    k_prep_wfrag<<<112, 256, 0, stream>>>(W_in, W_out, w_ih, w_hh, lp, W2,
                                          wo_hi, wih_hi, whh_hi,
                                          lp_hi, lp_lo, w2_hi, w2_lo);
    k_gnn<<<512, 512, 0, stream>>>(items, Amat, emb, b_in, b_out, b_iah, b_oah,
                                   wo_hi, wih_hi, whh_hi, b_ih, b_hh, hidnew);
    k_tail<<<512, 256, 0, stream>>>(alias, pos, hidnew,
                                    lp_hi, lp_lo, w2_hi, w2_lo, b2,
                                    W1, b1, W3, Wt, bt, pA_hi, pA_lo);
    k_pred_mfma<<<391, 512, 0, stream>>>(pA_hi, pA_lo, emb, outp);
}

// Round 15
// 169.822 us; speedup vs baseline: 1.0705x; 1.0289x over previous
//
#include <hip/hip_runtime.h>
#include <cstddef>
#include <cstdint>

#define NVOCAB 99999

typedef __attribute__((ext_vector_type(8))) short short8v;
typedef __attribute__((ext_vector_type(4))) short short4v;
typedef __attribute__((ext_vector_type(4))) float f32x4;

__device__ __forceinline__ float sigmoidf_(float x){ return 1.0f/(1.0f + __expf(-x)); }

__device__ __forceinline__ unsigned short bf16rn(float x){
    union { float f; uint32_t u; } v; v.f = x;
    uint32_t r = v.u + 0x7FFFu + ((v.u >> 16) & 1u);
    return (unsigned short)(r >> 16);
}

__device__ __forceinline__ void split_bf16(float x, unsigned short &hi, unsigned short &lo){
    hi = bf16rn(x);
    union { uint32_t u; float f; } hf; hf.u = ((uint32_t)hi) << 16;
    lo = bf16rn(x - hf.f);
}

__device__ __forceinline__ void split8(const float* xs, short8v &h, short8v &l){
    #pragma unroll
    for (int e = 0; e < 8; ++e){
        unsigned short uh, ul;
        split_bf16(xs[e], uh, ul);
        h[e] = (short)uh; l[e] = (short)ul;
    }
}

// ---------------- prep: split weights into B-fragment layout ----------------
__global__ __launch_bounds__(256) void k_prep_wfrag(
    const float* __restrict__ W_in, const float* __restrict__ W_out,
    const float* __restrict__ w_ih, const float* __restrict__ w_hh,
    const float* __restrict__ lp,  const float* __restrict__ W2,
    unsigned short* __restrict__ wo_hi,
    unsigned short* __restrict__ wih_hi,
    unsigned short* __restrict__ whh_hi,
    unsigned short* __restrict__ lp_hi,  unsigned short* __restrict__ lp_lo,
    unsigned short* __restrict__ w2_hi,  unsigned short* __restrict__ w2_lo)
{
    int id = blockIdx.x*256 + threadIdx.x;
    if (id < 4096){
        int lane=id&63, tile=id>>6, nt=tile>>2, ks=tile&3;
        int col=nt*16+(lane&15), k=ks*32+(lane>>4)*8;
        const float* src = (col<128) ? (W_in + (size_t)col*128 + k) : (W_out + (size_t)(col-128)*128 + k);
        float4 f0=*(const float4*)src, f1=*(const float4*)(src+4);
        float xs[8]={f0.x,f0.y,f0.z,f0.w,f1.x,f1.y,f1.z,f1.w};
        short8v h;
        #pragma unroll
        for (int e=0;e<8;++e) h[e]=(short)bf16rn(xs[e]);
        *(short8v*)(wo_hi+(size_t)id*8)=h;
    } else if (id < 16384){
        int t2=id-4096, lane=t2&63, tile=t2>>6, nt=tile>>3, ks=tile&7;
        int col=nt*16+(lane&15), k=ks*32+(lane>>4)*8;
        const float* src = w_ih + (size_t)col*256 + k;
        float4 f0=*(const float4*)src, f1=*(const float4*)(src+4);
        short8v h;
        float xs[8]={f0.x,f0.y,f0.z,f0.w,f1.x,f1.y,f1.z,f1.w};
        #pragma unroll
        for (int e=0;e<8;++e) h[e]=(short)bf16rn(xs[e]);
        *(short8v*)(wih_hi+(size_t)t2*8)=h;
    } else if (id < 22528){
        int t3=id-16384, lane=t3&63, tile=t3>>6, nt=tile>>2, ks=tile&3;
        int col=nt*16+(lane&15), k=ks*32+(lane>>4)*8;
        const float* src = w_hh + (size_t)col*128 + k;
        float4 f0=*(const float4*)src, f1=*(const float4*)(src+4);
        short8v h;
        float xs[8]={f0.x,f0.y,f0.z,f0.w,f1.x,f1.y,f1.z,f1.w};
        #pragma unroll
        for (int e=0;e<8;++e) h[e]=(short)bf16rn(xs[e]);
        *(short8v*)(whh_hi+(size_t)t3*8)=h;
    } else if (id < 26624){
        int t4=id-22528, lane=t4&63, tile=t4>>6, nt=tile>>3, ks=tile&7;
        int col=nt*16+(lane&15), k=ks*32+(lane>>4)*8;
        float xs[8];
        #pragma unroll
        for (int e=0;e<8;++e) xs[e]=lp[(size_t)(k+e)*128 + col];
        short8v h,l; split8(xs,h,l);
        *(short8v*)(lp_hi+(size_t)t4*8)=h; *(short8v*)(lp_lo+(size_t)t4*8)=l;
    } else if (id < 28672){
        int t5=id-26624, lane=t5&63, tile=t5>>6, nt=tile>>2, ks=tile&3;
        int col=nt*16+(lane&15), k=ks*32+(lane>>4)*8;
        const float* src = W2 + (size_t)col*128 + k;
        float4 f0=*(const float4*)src, f1=*(const float4*)(src+4);
        float xs[8]={f0.x,f0.y,f0.z,f0.w,f1.x,f1.y,f1.z,f1.w};
        short8v h,l; split8(xs,h,l);
        *(short8v*)(w2_hi+(size_t)t5*8)=h; *(short8v*)(w2_lo+(size_t)t5*8)=l;
    }
}

// ---------------- fused GNN: gather + hv + bmm + gi/gh GEMM + GRU gate -> hidnew ----------------
union SharedU {
    struct { unsigned short hi[256][72]; } hvT;  // 36864 B (hi-only)
    float inp[64][268];                          // 68608 B
};

__global__ __launch_bounds__(512,1) void k_gnn(
    const int* __restrict__ items, const float* __restrict__ Amat,
    const float* __restrict__ emb,
    const float* __restrict__ b_in, const float* __restrict__ b_out,
    const float* __restrict__ b_iah, const float* __restrict__ b_oah,
    const unsigned short* __restrict__ wo_hi,
    const unsigned short* __restrict__ wih_hi, const unsigned short* __restrict__ whh_hi,
    const float* __restrict__ b_ih, const float* __restrict__ b_hh,
    float* __restrict__ hidnew)
{
    const int t=threadIdx.x, lane=t&63, w=t>>6, bl=blockIdx.x;
    const int mi=w&3, ch=w>>2;
    const int c15=lane&15, g=lane>>4, kg=g*8;
    const int row=mi*16+c15;

    __shared__ int s_items[64];
    __shared__ float s_hid[64][132];
    __shared__ SharedU U;
    __shared__ unsigned short wbuf[2][24][512];

    if (t < 64) s_items[t]=items[bl*64+t];
    __syncthreads();

    // ---- phase 1: gather emb -> s_hid (f32) ----
    {
        int r=t>>3, c0=(t&7)*16;
        const float* src = emb + (size_t)s_items[r]*128 + c0;
        float4 v0=*(const float4*)(src);
        float4 v1=*(const float4*)(src+4);
        float4 v2=*(const float4*)(src+8);
        float4 v3=*(const float4*)(src+12);
        *(float4*)&s_hid[r][c0]   = v0;
        *(float4*)&s_hid[r][c0+4] = v1;
        *(float4*)&s_hid[r][c0+8] = v2;
        *(float4*)&s_hid[r][c0+12]= v3;
    }
    __syncthreads();

    short8v hhi[4], hlo[4];
    #pragma unroll
    for (int ks=0; ks<4; ++ks){
        const float* p=&s_hid[row][ks*32+kg];
        float4 f0=*(const float4*)p, f1=*(const float4*)(p+4);
        float xs[8]={f0.x,f0.y,f0.z,f0.w,f1.x,f1.y,f1.z,f1.w};
        split8(xs,hhi[ks],hlo[ks]);
    }

    // ---- phase 2: hv = hidden @ [W_in^T|W_out^T] + bias (weights hi-only, 2-product) ----
    {
        f32x4 acc[8];
        #pragma unroll
        for (int nt2=0;nt2<8;++nt2){
            int col=(ch*8+nt2)*16+c15;
            float bv=(col<128)? b_in[col] : b_out[col-128];
            acc[nt2]=(f32x4){bv,bv,bv,bv};
        }
        __builtin_amdgcn_s_setprio(1);
        #pragma unroll
        for (int ks=0; ks<4; ++ks){
            #pragma unroll
            for (int nt2=0; nt2<8; ++nt2){
                int nt=ch*8+nt2;
                size_t wo=((size_t)(nt*4+ks)*64+lane)*8;
                short8v bh=*(const short8v*)(wo_hi+wo);
                acc[nt2]=__builtin_amdgcn_mfma_f32_16x16x32_bf16(hhi[ks],bh,acc[nt2],0,0,0);
                acc[nt2]=__builtin_amdgcn_mfma_f32_16x16x32_bf16(hlo[ks],bh,acc[nt2],0,0,0);
            }
        }
        __builtin_amdgcn_s_setprio(0);
        const int r0=g*4;
        #pragma unroll
        for (int nt2=0;nt2<8;++nt2){
            int col=(ch*8+nt2)*16+c15;
            short4v h4;
            #pragma unroll
            for (int j=0;j<4;++j) h4[j]=(short)bf16rn(acc[nt2][j]);
            *(short4v*)&U.hvT.hi[col][mi*16+r0] = h4;
        }
    }
    __syncthreads();

    // ---- phase 3: bmm inputs = A @ hv + bias (hv hi-only, A split 2-product) ----
    f32x4 acc2[8];
    {
        #pragma unroll
        for (int nt2=0;nt2<8;++nt2){
            int col=(ch*8+nt2)*16+c15;
            float bv=(col<128)? b_iah[col] : b_oah[col-128];
            acc2[nt2]=(f32x4){bv,bv,bv,bv};
        }
        short8v ahi[2], alo[2];
        const float* Ab = Amat + (size_t)bl*8192 + (size_t)row*128 + (ch?64:0);
        #pragma unroll
        for (int ks=0;ks<2;++ks){
            float4 f0=*(const float4*)(Ab+ks*32+kg);
            float4 f1=*(const float4*)(Ab+ks*32+kg+4);
            float xs[8]={f0.x,f0.y,f0.z,f0.w,f1.x,f1.y,f1.z,f1.w};
            split8(xs,ahi[ks],alo[ks]);
        }
        __builtin_amdgcn_s_setprio(1);
        #pragma unroll
        for (int ks=0;ks<2;++ks){
            #pragma unroll
            for (int nt2=0;nt2<8;++nt2){
                int h=(ch*8+nt2)*16+c15;
                int m0=ks*32+kg;
                short8v bh=*(const short8v*)&U.hvT.hi[h][m0];
                acc2[nt2]=__builtin_amdgcn_mfma_f32_16x16x32_bf16(ahi[ks],bh,acc2[nt2],0,0,0);
                acc2[nt2]=__builtin_amdgcn_mfma_f32_16x16x32_bf16(alo[ks],bh,acc2[nt2],0,0,0);
            }
        }
        __builtin_amdgcn_s_setprio(0);
    }
    __syncthreads();

    // ---- phase 4: inputs f32 -> LDS (C-layout transpose) ----
    {
        #pragma unroll
        for (int nt2=0;nt2<8;++nt2){
            int col=(ch*8+nt2)*16+c15;
            #pragma unroll
            for (int j=0;j<4;++j)
                U.inp[mi*16+g*4+j][col]=acc2[nt2][j];
        }
    }

    // ---- phase 5: gi/gh GEMM (weights streamed via LDS, hi-only, 2-product) ----
    auto stage=[&](int ks, int buf){
        #pragma unroll
        for (int i=0;i<3;++i){
            int idx=i*512+t;
            int nt=idx>>6, ln=idx&63;
            const unsigned short *sh;
            if (ks<4){ sh = whh_hi + ((size_t)(nt*4+ks)*64+ln)*8; }
            else     { sh = wih_hi + ((size_t)(nt*8+(ks-4))*64+ln)*8; }
            *(short8v*)&wbuf[buf][nt][ln*8] = *(const short8v*)sh;
        }
    };

    f32x4 agi[12], agh[12];
    #pragma unroll
    for (int j=0;j<12;++j){
        int nt=(j>>2)*8 + ch*4 + (j&3);
        int col=nt*16+c15;
        float bi=b_ih[col], bh=b_hh[col];
        agi[j]=(f32x4){bi,bi,bi,bi};
        agh[j]=(f32x4){bh,bh,bh,bh};
    }

    stage(0,0);
    __syncthreads();
    for (int ks=0; ks<12; ++ks){
        int buf=ks&1;
        if (ks<11) stage(ks+1, buf^1);
        short8v ah, al;
        if (ks<4){
            ah=hhi[ks]; al=hlo[ks];
        } else {
            const float* p=&U.inp[row][(ks-4)*32+kg];
            float4 f0=*(const float4*)p, f1=*(const float4*)(p+4);
            float xs[8]={f0.x,f0.y,f0.z,f0.w,f1.x,f1.y,f1.z,f1.w};
            split8(xs,ah,al);
        }
        __builtin_amdgcn_s_setprio(1);
        if (ks<4){
            #pragma unroll
            for (int j=0;j<12;++j){
                int nt=(j>>2)*8 + ch*4 + (j&3);
                short8v bh=*(const short8v*)&wbuf[buf][nt][lane*8];
                agh[j]=__builtin_amdgcn_mfma_f32_16x16x32_bf16(ah,bh,agh[j],0,0,0);
                agh[j]=__builtin_amdgcn_mfma_f32_16x16x32_bf16(al,bh,agh[j],0,0,0);
            }
        } else {
            #pragma unroll
            for (int j=0;j<12;++j){
                int nt=(j>>2)*8 + ch*4 + (j&3);
                short8v bh=*(const short8v*)&wbuf[buf][nt][lane*8];
                agi[j]=__builtin_amdgcn_mfma_f32_16x16x32_bf16(ah,bh,agi[j],0,0,0);
                agi[j]=__builtin_amdgcn_mfma_f32_16x16x32_bf16(al,bh,agi[j],0,0,0);
            }
        }
        __builtin_amdgcn_s_setprio(0);
        __syncthreads();
    }

    // ---- phase 6: fused GRU gate -> hidnew ----
    const int r0=mi*16+g*4;
    #pragma unroll
    for (int sub=0;sub<4;++sub){
        int h=(ch*4+sub)*16+c15;
        #pragma unroll
        for (int j2=0;j2<4;++j2){
            float ir=agi[sub][j2], ii=agi[4+sub][j2], in_=agi[8+sub][j2];
            float hr=agh[sub][j2], hi_=agh[4+sub][j2], hn=agh[8+sub][j2];
            float rg=sigmoidf_(ir+hr), ig=sigmoidf_(ii+hi_);
            float ng=tanhf(in_+rg*hn);
            float ho=s_hid[r0+j2][h];
            hidnew[(size_t)(bl*64+r0+j2)*128+h]=ng+ig*(ho-ng);
        }
    }
}

// ---------------- fused tail: seq + q1/q2 + attention + afin -> pA frags ----------------
__global__ __launch_bounds__(256) void k_tail(
    const int* __restrict__ alias, const float* __restrict__ pos,
    const float* __restrict__ hn,
    const unsigned short* __restrict__ lp_hi, const unsigned short* __restrict__ lp_lo,
    const unsigned short* __restrict__ w2_hi, const unsigned short* __restrict__ w2_lo,
    const float* __restrict__ b2,
    const float* __restrict__ W1, const float* __restrict__ b1,
    const float* __restrict__ W3,
    const float* __restrict__ Wt, const float* __restrict__ bt,
    unsigned short* __restrict__ pA_hi, unsigned short* __restrict__ pA_lo)
{
    const int t=threadIdx.x, lane=t&63, w=t>>6, b=blockIdx.x;
    const int c15=lane&15, g=lane>>4;

    __shared__ union { float X[64][260]; float S[64][132]; } U;
    __shared__ int s_alias[64];
    __shared__ float s_q1[128], s_ht[128], s_alpha[64], s_a[128];
    __shared__ float s_pp[2][128];
    __shared__ int s_last;

    if (t<64) s_alias[t]=alias[b*64+t];
    __syncthreads();
    if (t==0){
        int c=0;
        for (int l=0;l<64;++l) c += (s_alias[l]>0) ? 1 : 0;
        s_last=(c-1)&63;
    }
    #pragma unroll
    for (int c=0;c<8;++c){
        int flat=c*1024+t*4, l=flat>>7, k=flat&127;
        *(float4*)&U.X[l][k] = *(const float4*)(pos + l*128 + k);
        int row=s_alias[l];
        *(float4*)&U.X[l][128+k] = *(const float4*)(hn + (size_t)(b*64 + row)*128 + k);
    }
    __syncthreads();

    f32x4 acc[8];
    #pragma unroll
    for (int nt=0;nt<8;++nt) acc[nt]=(f32x4){0.f,0.f,0.f,0.f};
    #pragma unroll
    for (int ks=0;ks<8;++ks){
        const float* xp=&U.X[w*16+c15][ks*32+g*8];
        float4 f0=*(const float4*)xp, f1=*(const float4*)(xp+4);
        float xs[8]={f0.x,f0.y,f0.z,f0.w,f1.x,f1.y,f1.z,f1.w};
        short8v ah,al; split8(xs,ah,al);
        #pragma unroll
        for (int nt=0;nt<8;++nt){
            size_t off=((size_t)(nt*8+ks)*64+lane)*8;
            short8v bh=*(const short8v*)(lp_hi+off);
            short8v bl_=*(const short8v*)(lp_lo+off);
            acc[nt]=__builtin_amdgcn_mfma_f32_16x16x32_bf16(ah,bh,acc[nt],0,0,0);
            acc[nt]=__builtin_amdgcn_mfma_f32_16x16x32_bf16(al,bh,acc[nt],0,0,0);
            acc[nt]=__builtin_amdgcn_mfma_f32_16x16x32_bf16(ah,bl_,acc[nt],0,0,0);
        }
    }
    float pj[4]={0.f,0.f,0.f,0.f};
    #pragma unroll
    for (int nt=0;nt<8;++nt){
        #pragma unroll
        for (int j=0;j<4;++j){
            float v=tanhf(acc[nt][j]);
            acc[nt][j]=v;
            pj[j]=fmaf(v,v,pj[j]);
        }
    }
    #pragma unroll
    for (int m=1;m<16;m<<=1){
        #pragma unroll
        for (int j=0;j<4;++j) pj[j]+=__shfl_xor(pj[j],m,64);
    }
    float rn[4];
    #pragma unroll
    for (int j=0;j<4;++j) rn[j]=rsqrtf(pj[j]);

    __syncthreads();
    #pragma unroll
    for (int nt=0;nt<8;++nt){
        #pragma unroll
        for (int j=0;j<4;++j)
            U.S[w*16+g*4+j][nt*16+c15]=acc[nt][j]*rn[j];
    }
    __syncthreads();

    if (t<128) s_ht[t]=U.S[s_last][t];
    __syncthreads();

    {
        int h=t&127, half=t>>7;
        float o=0.f;
        const float* wr=W1+(size_t)h*128+half*64;
        const float* hp=s_ht+half*64;
        #pragma unroll 8
        for (int k=0;k<64;k+=4){
            float4 wv=*(const float4*)(wr+k);
            o += hp[k]*wv.x + hp[k+1]*wv.y + hp[k+2]*wv.z + hp[k+3]*wv.w;
        }
        s_pp[half][h]=o;
    }
    __syncthreads();
    if (t<128) s_q1[t]=b1[t]+s_pp[0][t]+s_pp[1][t];

    f32x4 acc2[8];
    #pragma unroll
    for (int nt=0;nt<8;++nt){
        float bv=b2[nt*16+c15];
        acc2[nt]=(f32x4){bv,bv,bv,bv};
    }
    #pragma unroll
    for (int ks=0;ks<4;++ks){
        const float* sp=&U.S[w*16+c15][ks*32+g*8];
        float4 f0=*(const float4*)sp, f1=*(const float4*)(sp+4);
        float xs[8]={f0.x,f0.y,f0.z,f0.w,f1.x,f1.y,f1.z,f1.w};
        short8v ah,al; split8(xs,ah,al);
        #pragma unroll
        for (int nt=0;nt<8;++nt){
            size_t off=((size_t)(nt*4+ks)*64+lane)*8;
            short8v bh=*(const short8v*)(w2_hi+off);
            short8v bl_=*(const short8v*)(w2_lo+off);
            acc2[nt]=__builtin_amdgcn_mfma_f32_16x16x32_bf16(ah,bh,acc2[nt],0,0,0);
            acc2[nt]=__builtin_amdgcn_mfma_f32_16x16x32_bf16(al,bh,acc2[nt],0,0,0);
            acc2[nt]=__builtin_amdgcn_mfma_f32_16x16x32_bf16(ah,bl_,acc2[nt],0,0,0);
        }
    }
    __syncthreads();

    {
        float pa[4]={0.f,0.f,0.f,0.f};
        #pragma unroll
        for (int nt=0;nt<8;++nt){
            int col=nt*16+c15;
            float w3v=W3[col];
            #pragma unroll
            for (int j=0;j<4;++j)
                pa[j]=fmaf(sigmoidf_(s_q1[col]+acc2[nt][j]), w3v, pa[j]);
        }
        #pragma unroll
        for (int m=1;m<16;m<<=1){
            #pragma unroll
            for (int j=0;j<4;++j) pa[j]+=__shfl_xor(pa[j],m,64);
        }
        if (c15==0){
            #pragma unroll
            for (int j=0;j<4;++j){
                int l=w*16+g*4+j;
                s_alpha[l]=(s_alias[l]>0)? pa[j] : 0.f;
            }
        }
    }
    __syncthreads();

    {
        int h=t&127, half=t>>7;
        float a_=0.f;
        #pragma unroll 8
        for (int l=half*32;l<half*32+32;++l) a_=fmaf(s_alpha[l],U.S[l][h],a_);
        s_pp[half][h]=a_;
    }
    __syncthreads();
    if (t<128) s_a[t]=s_pp[0][t]+s_pp[1][t];
    __syncthreads();

    {
        int h=t&127, half=t>>7;
        float o=0.f;
        const float* wr=Wt+(size_t)h*256+half*128;
        const float* vp=(half==0)? s_a : s_ht;
        #pragma unroll 8
        for (int k=0;k<128;k+=4){
            float4 wv=*(const float4*)(wr+k);
            o += vp[k]*wv.x + vp[k+1]*wv.y + vp[k+2]*wv.z + vp[k+3]*wv.w;
        }
        s_pp[half][h]=o;
    }
    __syncthreads();
    if (t<128){
        float o=bt[t]+s_pp[0][t]+s_pp[1][t];
        unsigned short hi,lo; split_bf16(o,hi,lo);
        int mt=b>>4, r15=b&15;
        int ks=t>>5, gg=(t>>3)&3, e=t&7;
        int lz=gg*16+r15;
        size_t off=(((size_t)mt*4+ks)*64+lz)*8+e;
        pA_hi[off]=hi; pA_lo[off]=lo;
    }
}

// ---------------- pred v3: inline emb->bf16 conversion, stripe-resident B, rg loop ----------------
__global__ __launch_bounds__(512,1) void k_pred_mfma(
    const unsigned short* __restrict__ Ahi, const unsigned short* __restrict__ Alo,
    const float* __restrict__ emb, float* __restrict__ outp)
{
    const int t=threadIdx.x, lane=t&63, w=t>>6;
    const int st=blockIdx.x;
    const int c15=lane&15, g=lane>>4;

    __shared__ unsigned short Bsh[32768];
    __shared__ float S[8][8][264];

    #pragma unroll
    for (int p=0;p<16;++p){
        int c = p*512 + t;
        int r = c>>5, k0 = (c&31)*4;
        int v = st*256 + r;
        int srcr = (v < NVOCAB) ? (v+1) : 0;
        float4 f = *(const float4*)(emb + (size_t)srcr*128 + k0);
        int q_s = (r>>6)*16 + ((r>>4)&3)*4 + (k0>>5);
        int ln  = ((k0>>3)&3)*16 + (r&15);
        short4v h4;
        h4[0]=(short)bf16rn(f.x); h4[1]=(short)bf16rn(f.y);
        h4[2]=(short)bf16rn(f.z); h4[3]=(short)bf16rn(f.w);
        *(short4v*)&Bsh[(q_s*64+ln)*8 + (k0&7)] = h4;
    }
    __syncthreads();

    for (int rg=0; rg<4; ++rg){
        const int mt = rg*8 + w;
        short8v ahi[4], alo[4];
        #pragma unroll
        for (int ks=0;ks<4;++ks){
            size_t off=((size_t)(mt*4+ks)*64+lane)*8;
            ahi[ks]=*(const short8v*)(Ahi+off);
            alo[ks]=*(const short8v*)(Alo+off);
        }

        f32x4 acc[16];
        __builtin_amdgcn_s_setprio(1);
        #pragma unroll
        for (int ntl=0;ntl<16;++ntl){
            acc[ntl]=(f32x4){0.f,0.f,0.f,0.f};
            #pragma unroll
            for (int ks=0;ks<4;++ks){
                short8v bh = *(const short8v*)&Bsh[(size_t)((ntl*4+ks)*64 + lane)*8];
                acc[ntl]=__builtin_amdgcn_mfma_f32_16x16x32_bf16(ahi[ks],bh,acc[ntl],0,0,0);
                acc[ntl]=__builtin_amdgcn_mfma_f32_16x16x32_bf16(alo[ks],bh,acc[ntl],0,0,0);
            }
        }
        __builtin_amdgcn_s_setprio(0);

        #pragma unroll
        for (int hh=0; hh<2; ++hh){
            if ((g>>1) == hh){
                int rloc=(g&1)*4;
                #pragma unroll
                for (int ntl=0;ntl<16;++ntl){
                    #pragma unroll
                    for (int j=0;j<4;++j)
                        S[w][rloc+j][ntl*16+c15] = 16.0f*acc[ntl][j];
                }
            }
            __syncthreads();
            #pragma unroll
            for (int p=0;p<8;++p){
                int row = mt*16 + hh*8 + p;
                int col0 = st*256 + lane*4;
                f32x4 o = *(f32x4*)&S[w][p][lane*4];
                size_t rowoff = (size_t)row*NVOCAB;
                if (col0 + 3 < NVOCAB){
                    __builtin_nontemporal_store(o, (f32x4*)(outp + rowoff + col0));
                } else {
                    #pragma unroll
                    for (int cc2=0;cc2<4;++cc2)
                        if (col0+cc2 < NVOCAB) outp[rowoff + col0 + cc2] = o[cc2];
                }
            }
            __syncthreads();
        }
    }
}

extern "C" void kernel_launch(void* const* d_in, const int* in_sizes, int n_in,
                              void* d_out, int out_size, void* d_ws, size_t ws_size,
                              hipStream_t stream)
{
    const int*   items = (const int*)  d_in[0];
    const float* Amat  = (const float*)d_in[1];
    const int*   alias = (const int*)  d_in[2];
    const float* emb   = (const float*)d_in[3];
    const float* pos   = (const float*)d_in[4];
    const float* lp    = (const float*)d_in[5];
    const float* w_ih  = (const float*)d_in[6];
    const float* w_hh  = (const float*)d_in[7];
    const float* b_ih  = (const float*)d_in[8];
    const float* b_hh  = (const float*)d_in[9];
    const float* b_iah = (const float*)d_in[10];
    const float* b_oah = (const float*)d_in[11];
    const float* W_in  = (const float*)d_in[12];
    const float* b_in  = (const float*)d_in[13];
    const float* W_out = (const float*)d_in[14];
    const float* b_out = (const float*)d_in[15];
    const float* W1    = (const float*)d_in[16];
    const float* b1    = (const float*)d_in[17];
    const float* W2    = (const float*)d_in[18];
    const float* b2    = (const float*)d_in[19];
    const float* W3    = (const float*)d_in[20];
    const float* Wt    = (const float*)d_in[21];
    const float* bt    = (const float*)d_in[22];
    float* outp = (float*)d_out;

    // ---- workspace carve ----
    float* wsf = (float*)d_ws;
    size_t o = 0;
    float* hidnew = wsf + o;               o += 4194304;
    unsigned short* us = (unsigned short*)(wsf + o);
    size_t uo = 0;
    unsigned short* wo_hi  = us + uo; uo += 32768;
    unsigned short* wih_hi = us + uo; uo += 98304;
    unsigned short* whh_hi = us + uo; uo += 49152;
    unsigned short* lp_hi  = us + uo; uo += 32768;
    unsigned short* lp_lo  = us + uo; uo += 32768;
    unsigned short* w2_hi  = us + uo; uo += 16384;
    unsigned short* w2_lo  = us + uo; uo += 16384;
    unsigned short* pA_hi  = us + uo; uo += 65536;
    unsigned short* pA_lo  = us + uo; uo += 65536;

    k_prep_wfrag<<<112, 256, 0, stream>>>(W_in, W_out, w_ih, w_hh, lp, W2,
                                          wo_hi, wih_hi, whh_hi,
                                          lp_hi, lp_lo, w2_hi, w2_lo);
    k_gnn<<<512, 512, 0, stream>>>(items, Amat, emb, b_in, b_out, b_iah, b_oah,
                                   wo_hi, wih_hi, whh_hi, b_ih, b_hh, hidnew);
    k_tail<<<512, 256, 0, stream>>>(alias, pos, hidnew,
                                    lp_hi, lp_lo, w2_hi, w2_lo, b2,
                                    W1, b1, W3, Wt, bt, pA_hi, pA_lo);
    k_pred_mfma<<<391, 512, 0, stream>>>(pA_hi, pA_lo, emb, outp);
}

// Round 16
// 159.467 us; speedup vs baseline: 1.1400x; 1.0649x over previous
//
#include <hip/hip_runtime.h>
#include <cstddef>
#include <cstdint>

#define NVOCAB 99999

typedef __attribute__((ext_vector_type(8))) short short8v;
typedef __attribute__((ext_vector_type(4))) short short4v;
typedef __attribute__((ext_vector_type(4))) float f32x4;

__device__ __forceinline__ float sigmoidf_(float x){ return 1.0f/(1.0f + __expf(-x)); }

__device__ __forceinline__ unsigned short bf16rn(float x){
    union { float f; uint32_t u; } v; v.f = x;
    uint32_t r = v.u + 0x7FFFu + ((v.u >> 16) & 1u);
    return (unsigned short)(r >> 16);
}

__device__ __forceinline__ void split_bf16(float x, unsigned short &hi, unsigned short &lo){
    hi = bf16rn(x);
    union { uint32_t u; float f; } hf; hf.u = ((uint32_t)hi) << 16;
    lo = bf16rn(x - hf.f);
}

__device__ __forceinline__ void split8(const float* xs, short8v &h, short8v &l){
    #pragma unroll
    for (int e = 0; e < 8; ++e){
        unsigned short uh, ul;
        split_bf16(xs[e], uh, ul);
        h[e] = (short)uh; l[e] = (short)ul;
    }
}

// ---------------- prep: weights -> bf16 B-fragments (all hi-only now) ----------------
__global__ __launch_bounds__(256) void k_prep_wfrag(
    const float* __restrict__ W_in, const float* __restrict__ W_out,
    const float* __restrict__ w_ih, const float* __restrict__ w_hh,
    const float* __restrict__ lp,  const float* __restrict__ W2,
    unsigned short* __restrict__ wo_hi,
    unsigned short* __restrict__ wih_hi,
    unsigned short* __restrict__ whh_hi,
    unsigned short* __restrict__ lp_hi,
    unsigned short* __restrict__ w2_hi)
{
    int id = blockIdx.x*256 + threadIdx.x;
    if (id < 4096){
        int lane=id&63, tile=id>>6, nt=tile>>2, ks=tile&3;
        int col=nt*16+(lane&15), k=ks*32+(lane>>4)*8;
        const float* src = (col<128) ? (W_in + (size_t)col*128 + k) : (W_out + (size_t)(col-128)*128 + k);
        float4 f0=*(const float4*)src, f1=*(const float4*)(src+4);
        float xs[8]={f0.x,f0.y,f0.z,f0.w,f1.x,f1.y,f1.z,f1.w};
        short8v h;
        #pragma unroll
        for (int e=0;e<8;++e) h[e]=(short)bf16rn(xs[e]);
        *(short8v*)(wo_hi+(size_t)id*8)=h;
    } else if (id < 16384){
        int t2=id-4096, lane=t2&63, tile=t2>>6, nt=tile>>3, ks=tile&7;
        int col=nt*16+(lane&15), k=ks*32+(lane>>4)*8;
        const float* src = w_ih + (size_t)col*256 + k;
        float4 f0=*(const float4*)src, f1=*(const float4*)(src+4);
        short8v h;
        float xs[8]={f0.x,f0.y,f0.z,f0.w,f1.x,f1.y,f1.z,f1.w};
        #pragma unroll
        for (int e=0;e<8;++e) h[e]=(short)bf16rn(xs[e]);
        *(short8v*)(wih_hi+(size_t)t2*8)=h;
    } else if (id < 22528){
        int t3=id-16384, lane=t3&63, tile=t3>>6, nt=tile>>2, ks=tile&3;
        int col=nt*16+(lane&15), k=ks*32+(lane>>4)*8;
        const float* src = w_hh + (size_t)col*128 + k;
        float4 f0=*(const float4*)src, f1=*(const float4*)(src+4);
        short8v h;
        float xs[8]={f0.x,f0.y,f0.z,f0.w,f1.x,f1.y,f1.z,f1.w};
        #pragma unroll
        for (int e=0;e<8;++e) h[e]=(short)bf16rn(xs[e]);
        *(short8v*)(whh_hi+(size_t)t3*8)=h;
    } else if (id < 26624){
        int t4=id-22528, lane=t4&63, tile=t4>>6, nt=tile>>3, ks=tile&7;
        int col=nt*16+(lane&15), k=ks*32+(lane>>4)*8;
        float xs[8];
        #pragma unroll
        for (int e=0;e<8;++e) xs[e]=lp[(size_t)(k+e)*128 + col];
        short8v h;
        #pragma unroll
        for (int e=0;e<8;++e) h[e]=(short)bf16rn(xs[e]);
        *(short8v*)(lp_hi+(size_t)t4*8)=h;
    } else if (id < 28672){
        int t5=id-26624, lane=t5&63, tile=t5>>6, nt=tile>>2, ks=tile&3;
        int col=nt*16+(lane&15), k=ks*32+(lane>>4)*8;
        const float* src = W2 + (size_t)col*128 + k;
        float4 f0=*(const float4*)src, f1=*(const float4*)(src+4);
        float xs[8]={f0.x,f0.y,f0.z,f0.w,f1.x,f1.y,f1.z,f1.w};
        short8v h;
        #pragma unroll
        for (int e=0;e<8;++e) h[e]=(short)bf16rn(xs[e]);
        *(short8v*)(w2_hi+(size_t)t5*8)=h;
    }
}

// ---------------- fused GNN: gather + hv + bmm + gi/gh GEMM + GRU gate -> hidnew ----------------
union SharedU {
    struct { unsigned short hi[256][72]; } hvT;  // 36864 B (hi-only)
    float inp[64][268];                          // 68608 B
};

__global__ __launch_bounds__(512,1) void k_gnn(
    const int* __restrict__ items, const float* __restrict__ Amat,
    const float* __restrict__ emb,
    const float* __restrict__ b_in, const float* __restrict__ b_out,
    const float* __restrict__ b_iah, const float* __restrict__ b_oah,
    const unsigned short* __restrict__ wo_hi,
    const unsigned short* __restrict__ wih_hi, const unsigned short* __restrict__ whh_hi,
    const float* __restrict__ b_ih, const float* __restrict__ b_hh,
    float* __restrict__ hidnew)
{
    const int t=threadIdx.x, lane=t&63, w=t>>6, bl=blockIdx.x;
    const int mi=w&3, ch=w>>2;
    const int c15=lane&15, g=lane>>4, kg=g*8;
    const int row=mi*16+c15;

    __shared__ int s_items[64];
    __shared__ float s_hid[64][132];
    __shared__ SharedU U;
    __shared__ unsigned short wbuf[2][24][512];

    if (t < 64) s_items[t]=items[bl*64+t];
    __syncthreads();

    // ---- phase 1: gather emb -> s_hid (f32) ----
    {
        int r=t>>3, c0=(t&7)*16;
        const float* src = emb + (size_t)s_items[r]*128 + c0;
        float4 v0=*(const float4*)(src);
        float4 v1=*(const float4*)(src+4);
        float4 v2=*(const float4*)(src+8);
        float4 v3=*(const float4*)(src+12);
        *(float4*)&s_hid[r][c0]   = v0;
        *(float4*)&s_hid[r][c0+4] = v1;
        *(float4*)&s_hid[r][c0+8] = v2;
        *(float4*)&s_hid[r][c0+12]= v3;
    }
    __syncthreads();

    short8v hhi[4], hlo[4];
    #pragma unroll
    for (int ks=0; ks<4; ++ks){
        const float* p=&s_hid[row][ks*32+kg];
        float4 f0=*(const float4*)p, f1=*(const float4*)(p+4);
        float xs[8]={f0.x,f0.y,f0.z,f0.w,f1.x,f1.y,f1.z,f1.w};
        split8(xs,hhi[ks],hlo[ks]);
    }

    // ---- phase 2: hv = hidden @ [W_in^T|W_out^T] + bias (weights hi-only, 2-product) ----
    {
        f32x4 acc[8];
        #pragma unroll
        for (int nt2=0;nt2<8;++nt2){
            int col=(ch*8+nt2)*16+c15;
            float bv=(col<128)? b_in[col] : b_out[col-128];
            acc[nt2]=(f32x4){bv,bv,bv,bv};
        }
        __builtin_amdgcn_s_setprio(1);
        #pragma unroll
        for (int ks=0; ks<4; ++ks){
            #pragma unroll
            for (int nt2=0; nt2<8; ++nt2){
                int nt=ch*8+nt2;
                size_t wo=((size_t)(nt*4+ks)*64+lane)*8;
                short8v bh=*(const short8v*)(wo_hi+wo);
                acc[nt2]=__builtin_amdgcn_mfma_f32_16x16x32_bf16(hhi[ks],bh,acc[nt2],0,0,0);
                acc[nt2]=__builtin_amdgcn_mfma_f32_16x16x32_bf16(hlo[ks],bh,acc[nt2],0,0,0);
            }
        }
        __builtin_amdgcn_s_setprio(0);
        const int r0=g*4;
        #pragma unroll
        for (int nt2=0;nt2<8;++nt2){
            int col=(ch*8+nt2)*16+c15;
            short4v h4;
            #pragma unroll
            for (int j=0;j<4;++j) h4[j]=(short)bf16rn(acc[nt2][j]);
            *(short4v*)&U.hvT.hi[col][mi*16+r0] = h4;
        }
    }
    __syncthreads();

    // ---- phase 3: bmm inputs = A @ hv + bias (hv hi-only, A split 2-product) ----
    f32x4 acc2[8];
    {
        #pragma unroll
        for (int nt2=0;nt2<8;++nt2){
            int col=(ch*8+nt2)*16+c15;
            float bv=(col<128)? b_iah[col] : b_oah[col-128];
            acc2[nt2]=(f32x4){bv,bv,bv,bv};
        }
        short8v ahi[2], alo[2];
        const float* Ab = Amat + (size_t)bl*8192 + (size_t)row*128 + (ch?64:0);
        #pragma unroll
        for (int ks=0;ks<2;++ks){
            float4 f0=*(const float4*)(Ab+ks*32+kg);
            float4 f1=*(const float4*)(Ab+ks*32+kg+4);
            float xs[8]={f0.x,f0.y,f0.z,f0.w,f1.x,f1.y,f1.z,f1.w};
            split8(xs,ahi[ks],alo[ks]);
        }
        __builtin_amdgcn_s_setprio(1);
        #pragma unroll
        for (int ks=0;ks<2;++ks){
            #pragma unroll
            for (int nt2=0;nt2<8;++nt2){
                int h=(ch*8+nt2)*16+c15;
                int m0=ks*32+kg;
                short8v bh=*(const short8v*)&U.hvT.hi[h][m0];
                acc2[nt2]=__builtin_amdgcn_mfma_f32_16x16x32_bf16(ahi[ks],bh,acc2[nt2],0,0,0);
                acc2[nt2]=__builtin_amdgcn_mfma_f32_16x16x32_bf16(alo[ks],bh,acc2[nt2],0,0,0);
            }
        }
        __builtin_amdgcn_s_setprio(0);
    }
    __syncthreads();

    // ---- phase 4: inputs f32 -> LDS (C-layout transpose) ----
    {
        #pragma unroll
        for (int nt2=0;nt2<8;++nt2){
            int col=(ch*8+nt2)*16+c15;
            #pragma unroll
            for (int j=0;j<4;++j)
                U.inp[mi*16+g*4+j][col]=acc2[nt2][j];
        }
    }

    // ---- phase 5: gi/gh GEMM (weights streamed via LDS, hi-only, 2-product) ----
    auto stage=[&](int ks, int buf){
        #pragma unroll
        for (int i=0;i<3;++i){
            int idx=i*512+t;
            int nt=idx>>6, ln=idx&63;
            const unsigned short *sh;
            if (ks<4){ sh = whh_hi + ((size_t)(nt*4+ks)*64+ln)*8; }
            else     { sh = wih_hi + ((size_t)(nt*8+(ks-4))*64+ln)*8; }
            *(short8v*)&wbuf[buf][nt][ln*8] = *(const short8v*)sh;
        }
    };

    f32x4 agi[12], agh[12];
    #pragma unroll
    for (int j=0;j<12;++j){
        int nt=(j>>2)*8 + ch*4 + (j&3);
        int col=nt*16+c15;
        float bi=b_ih[col], bh=b_hh[col];
        agi[j]=(f32x4){bi,bi,bi,bi};
        agh[j]=(f32x4){bh,bh,bh,bh};
    }

    stage(0,0);
    __syncthreads();
    for (int ks=0; ks<12; ++ks){
        int buf=ks&1;
        if (ks<11) stage(ks+1, buf^1);
        short8v ah, al;
        if (ks<4){
            ah=hhi[ks]; al=hlo[ks];
        } else {
            const float* p=&U.inp[row][(ks-4)*32+kg];
            float4 f0=*(const float4*)p, f1=*(const float4*)(p+4);
            float xs[8]={f0.x,f0.y,f0.z,f0.w,f1.x,f1.y,f1.z,f1.w};
            split8(xs,ah,al);
        }
        __builtin_amdgcn_s_setprio(1);
        if (ks<4){
            #pragma unroll
            for (int j=0;j<12;++j){
                int nt=(j>>2)*8 + ch*4 + (j&3);
                short8v bh=*(const short8v*)&wbuf[buf][nt][lane*8];
                agh[j]=__builtin_amdgcn_mfma_f32_16x16x32_bf16(ah,bh,agh[j],0,0,0);
                agh[j]=__builtin_amdgcn_mfma_f32_16x16x32_bf16(al,bh,agh[j],0,0,0);
            }
        } else {
            #pragma unroll
            for (int j=0;j<12;++j){
                int nt=(j>>2)*8 + ch*4 + (j&3);
                short8v bh=*(const short8v*)&wbuf[buf][nt][lane*8];
                agi[j]=__builtin_amdgcn_mfma_f32_16x16x32_bf16(ah,bh,agi[j],0,0,0);
                agi[j]=__builtin_amdgcn_mfma_f32_16x16x32_bf16(al,bh,agi[j],0,0,0);
            }
        }
        __builtin_amdgcn_s_setprio(0);
        __syncthreads();
    }

    // ---- phase 6: fused GRU gate -> hidnew ----
    const int r0=mi*16+g*4;
    #pragma unroll
    for (int sub=0;sub<4;++sub){
        int h=(ch*4+sub)*16+c15;
        #pragma unroll
        for (int j2=0;j2<4;++j2){
            float ir=agi[sub][j2], ii=agi[4+sub][j2], in_=agi[8+sub][j2];
            float hr=agh[sub][j2], hi_=agh[4+sub][j2], hn=agh[8+sub][j2];
            float rg=sigmoidf_(ir+hr), ig=sigmoidf_(ii+hi_);
            float ng=tanhf(in_+rg*hn);
            float ho=s_hid[r0+j2][h];
            hidnew[(size_t)(bl*64+r0+j2)*128+h]=ng+ig*(ho-ng);
        }
    }
}

// ---------------- fused tail: seq + q1/q2 + attention + afin -> pA frags ----------------
__global__ __launch_bounds__(256) void k_tail(
    const int* __restrict__ alias, const float* __restrict__ pos,
    const float* __restrict__ hn,
    const unsigned short* __restrict__ lp_hi,
    const unsigned short* __restrict__ w2_hi,
    const float* __restrict__ b2,
    const float* __restrict__ W1, const float* __restrict__ b1,
    const float* __restrict__ W3,
    const float* __restrict__ Wt, const float* __restrict__ bt,
    unsigned short* __restrict__ pA_hi, unsigned short* __restrict__ pA_lo)
{
    const int t=threadIdx.x, lane=t&63, w=t>>6, b=blockIdx.x;
    const int c15=lane&15, g=lane>>4;

    __shared__ union { float X[64][260]; float S[64][132]; } U;
    __shared__ int s_alias[64];
    __shared__ float s_q1[128], s_ht[128], s_alpha[64], s_a[128];
    __shared__ float s_pp[2][128];
    __shared__ int s_last;

    if (t<64) s_alias[t]=alias[b*64+t];
    __syncthreads();
    if (t==0){
        int c=0;
        for (int l=0;l<64;++l) c += (s_alias[l]>0) ? 1 : 0;
        s_last=(c-1)&63;
    }
    #pragma unroll
    for (int c=0;c<8;++c){
        int flat=c*1024+t*4, l=flat>>7, k=flat&127;
        *(float4*)&U.X[l][k] = *(const float4*)(pos + l*128 + k);
        int row=s_alias[l];
        *(float4*)&U.X[l][128+k] = *(const float4*)(hn + (size_t)(b*64 + row)*128 + k);
    }
    __syncthreads();

    // ---- Y = tanh(X @ lp) (lp hi-only, 2-product) ----
    f32x4 acc[8];
    #pragma unroll
    for (int nt=0;nt<8;++nt) acc[nt]=(f32x4){0.f,0.f,0.f,0.f};
    #pragma unroll
    for (int ks=0;ks<8;++ks){
        const float* xp=&U.X[w*16+c15][ks*32+g*8];
        float4 f0=*(const float4*)xp, f1=*(const float4*)(xp+4);
        float xs[8]={f0.x,f0.y,f0.z,f0.w,f1.x,f1.y,f1.z,f1.w};
        short8v ah,al; split8(xs,ah,al);
        #pragma unroll
        for (int nt=0;nt<8;++nt){
            size_t off=((size_t)(nt*8+ks)*64+lane)*8;
            short8v bh=*(const short8v*)(lp_hi+off);
            acc[nt]=__builtin_amdgcn_mfma_f32_16x16x32_bf16(ah,bh,acc[nt],0,0,0);
            acc[nt]=__builtin_amdgcn_mfma_f32_16x16x32_bf16(al,bh,acc[nt],0,0,0);
        }
    }
    float pj[4]={0.f,0.f,0.f,0.f};
    #pragma unroll
    for (int nt=0;nt<8;++nt){
        #pragma unroll
        for (int j=0;j<4;++j){
            float v=tanhf(acc[nt][j]);
            acc[nt][j]=v;
            pj[j]=fmaf(v,v,pj[j]);
        }
    }
    #pragma unroll
    for (int m=1;m<16;m<<=1){
        #pragma unroll
        for (int j=0;j<4;++j) pj[j]+=__shfl_xor(pj[j],m,64);
    }
    float rn[4];
    #pragma unroll
    for (int j=0;j<4;++j) rn[j]=rsqrtf(pj[j]);

    __syncthreads();
    #pragma unroll
    for (int nt=0;nt<8;++nt){
        #pragma unroll
        for (int j=0;j<4;++j)
            U.S[w*16+g*4+j][nt*16+c15]=acc[nt][j]*rn[j];
    }
    __syncthreads();

    if (t<128) s_ht[t]=U.S[s_last][t];
    __syncthreads();

    {
        int h=t&127, half=t>>7;
        float o=0.f;
        const float* wr=W1+(size_t)h*128+half*64;
        const float* hp=s_ht+half*64;
        #pragma unroll 8
        for (int k=0;k<64;k+=4){
            float4 wv=*(const float4*)(wr+k);
            o += hp[k]*wv.x + hp[k+1]*wv.y + hp[k+2]*wv.z + hp[k+3]*wv.w;
        }
        s_pp[half][h]=o;
    }
    __syncthreads();
    if (t<128) s_q1[t]=b1[t]+s_pp[0][t]+s_pp[1][t];

    // ---- q2 = seq @ W2^T + b2 (W2 hi-only, 2-product) ----
    f32x4 acc2[8];
    #pragma unroll
    for (int nt=0;nt<8;++nt){
        float bv=b2[nt*16+c15];
        acc2[nt]=(f32x4){bv,bv,bv,bv};
    }
    #pragma unroll
    for (int ks=0;ks<4;++ks){
        const float* sp=&U.S[w*16+c15][ks*32+g*8];
        float4 f0=*(const float4*)sp, f1=*(const float4*)(sp+4);
        float xs[8]={f0.x,f0.y,f0.z,f0.w,f1.x,f1.y,f1.z,f1.w};
        short8v ah,al; split8(xs,ah,al);
        #pragma unroll
        for (int nt=0;nt<8;++nt){
            size_t off=((size_t)(nt*4+ks)*64+lane)*8;
            short8v bh=*(const short8v*)(w2_hi+off);
            acc2[nt]=__builtin_amdgcn_mfma_f32_16x16x32_bf16(ah,bh,acc2[nt],0,0,0);
            acc2[nt]=__builtin_amdgcn_mfma_f32_16x16x32_bf16(al,bh,acc2[nt],0,0,0);
        }
    }
    __syncthreads();

    {
        float pa[4]={0.f,0.f,0.f,0.f};
        #pragma unroll
        for (int nt=0;nt<8;++nt){
            int col=nt*16+c15;
            float w3v=W3[col];
            #pragma unroll
            for (int j=0;j<4;++j)
                pa[j]=fmaf(sigmoidf_(s_q1[col]+acc2[nt][j]), w3v, pa[j]);
        }
        #pragma unroll
        for (int m=1;m<16;m<<=1){
            #pragma unroll
            for (int j=0;j<4;++j) pa[j]+=__shfl_xor(pa[j],m,64);
        }
        if (c15==0){
            #pragma unroll
            for (int j=0;j<4;++j){
                int l=w*16+g*4+j;
                s_alpha[l]=(s_alias[l]>0)? pa[j] : 0.f;
            }
        }
    }
    __syncthreads();

    {
        int h=t&127, half=t>>7;
        float a_=0.f;
        #pragma unroll 8
        for (int l=half*32;l<half*32+32;++l) a_=fmaf(s_alpha[l],U.S[l][h],a_);
        s_pp[half][h]=a_;
    }
    __syncthreads();
    if (t<128) s_a[t]=s_pp[0][t]+s_pp[1][t];
    __syncthreads();

    {
        int h=t&127, half=t>>7;
        float o=0.f;
        const float* wr=Wt+(size_t)h*256+half*128;
        const float* vp=(half==0)? s_a : s_ht;
        #pragma unroll 8
        for (int k=0;k<128;k+=4){
            float4 wv=*(const float4*)(wr+k);
            o += vp[k]*wv.x + vp[k+1]*wv.y + vp[k+2]*wv.z + vp[k+3]*wv.w;
        }
        s_pp[half][h]=o;
    }
    __syncthreads();
    if (t<128){
        float o=bt[t]+s_pp[0][t]+s_pp[1][t];
        unsigned short hi,lo; split_bf16(o,hi,lo);
        int mt=b>>4, r15=b&15;
        int ks=t>>5, gg=(t>>3)&3, e=t&7;
        int lz=gg*16+r15;
        size_t off=(((size_t)mt*4+ks)*64+lz)*8+e;
        pA_hi[off]=hi; pA_lo[off]=lo;
    }
}

// ---------------- pred v3: inline emb->bf16 conversion, stripe-resident B, rg loop ----------------
__global__ __launch_bounds__(512,1) void k_pred_mfma(
    const unsigned short* __restrict__ Ahi, const unsigned short* __restrict__ Alo,
    const float* __restrict__ emb, float* __restrict__ outp)
{
    const int t=threadIdx.x, lane=t&63, w=t>>6;
    const int st=blockIdx.x;
    const int c15=lane&15, g=lane>>4;

    __shared__ unsigned short Bsh[32768];
    __shared__ float S[8][8][264];

    #pragma unroll
    for (int p=0;p<16;++p){
        int c = p*512 + t;
        int r = c>>5, k0 = (c&31)*4;
        int v = st*256 + r;
        int srcr = (v < NVOCAB) ? (v+1) : 0;
        float4 f = *(const float4*)(emb + (size_t)srcr*128 + k0);
        int q_s = (r>>6)*16 + ((r>>4)&3)*4 + (k0>>5);
        int ln  = ((k0>>3)&3)*16 + (r&15);
        short4v h4;
        h4[0]=(short)bf16rn(f.x); h4[1]=(short)bf16rn(f.y);
        h4[2]=(short)bf16rn(f.z); h4[3]=(short)bf16rn(f.w);
        *(short4v*)&Bsh[(q_s*64+ln)*8 + (k0&7)] = h4;
    }
    __syncthreads();

    for (int rg=0; rg<4; ++rg){
        const int mt = rg*8 + w;
        short8v ahi[4], alo[4];
        #pragma unroll
        for (int ks=0;ks<4;++ks){
            size_t off=((size_t)(mt*4+ks)*64+lane)*8;
            ahi[ks]=*(const short8v*)(Ahi+off);
            alo[ks]=*(const short8v*)(Alo+off);
        }

        f32x4 acc[16];
        __builtin_amdgcn_s_setprio(1);
        #pragma unroll
        for (int ntl=0;ntl<16;++ntl){
            acc[ntl]=(f32x4){0.f,0.f,0.f,0.f};
            #pragma unroll
            for (int ks=0;ks<4;++ks){
                short8v bh = *(const short8v*)&Bsh[(size_t)((ntl*4+ks)*64 + lane)*8];
                acc[ntl]=__builtin_amdgcn_mfma_f32_16x16x32_bf16(ahi[ks],bh,acc[ntl],0,0,0);
                acc[ntl]=__builtin_amdgcn_mfma_f32_16x16x32_bf16(alo[ks],bh,acc[ntl],0,0,0);
            }
        }
        __builtin_amdgcn_s_setprio(0);

        #pragma unroll
        for (int hh=0; hh<2; ++hh){
            if ((g>>1) == hh){
                int rloc=(g&1)*4;
                #pragma unroll
                for (int ntl=0;ntl<16;++ntl){
                    #pragma unroll
                    for (int j=0;j<4;++j)
                        S[w][rloc+j][ntl*16+c15] = 16.0f*acc[ntl][j];
                }
            }
            __syncthreads();
            #pragma unroll
            for (int p=0;p<8;++p){
                int row = mt*16 + hh*8 + p;
                int col0 = st*256 + lane*4;
                f32x4 o = *(f32x4*)&S[w][p][lane*4];
                size_t rowoff = (size_t)row*NVOCAB;
                if (col0 + 3 < NVOCAB){
                    __builtin_nontemporal_store(o, (f32x4*)(outp + rowoff + col0));
                } else {
                    #pragma unroll
                    for (int cc2=0;cc2<4;++cc2)
                        if (col0+cc2 < NVOCAB) outp[rowoff + col0 + cc2] = o[cc2];
                }
            }
            __syncthreads();
        }
    }
}

extern "C" void kernel_launch(void* const* d_in, const int* in_sizes, int n_in,
                              void* d_out, int out_size, void* d_ws, size_t ws_size,
                              hipStream_t stream)
{
    const int*   items = (const int*)  d_in[0];
    const float* Amat  = (const float*)d_in[1];
    const int*   alias = (const int*)  d_in[2];
    const float* emb   = (const float*)d_in[3];
    const float* pos   = (const float*)d_in[4];
    const float* lp    = (const float*)d_in[5];
    const float* w_ih  = (const float*)d_in[6];
    const float* w_hh  = (const float*)d_in[7];
    const float* b_ih  = (const float*)d_in[8];
    const float* b_hh  = (const float*)d_in[9];
    const float* b_iah = (const float*)d_in[10];
    const float* b_oah = (const float*)d_in[11];
    const float* W_in  = (const float*)d_in[12];
    const float* b_in  = (const float*)d_in[13];
    const float* W_out = (const float*)d_in[14];
    const float* b_out = (const float*)d_in[15];
    const float* W1    = (const float*)d_in[16];
    const float* b1    = (const float*)d_in[17];
    const float* W2    = (const float*)d_in[18];
    const float* b2    = (const float*)d_in[19];
    const float* W3    = (const float*)d_in[20];
    const float* Wt    = (const float*)d_in[21];
    const float* bt    = (const float*)d_in[22];
    float* outp = (float*)d_out;

    // ---- workspace carve ----
    float* wsf = (float*)d_ws;
    size_t o = 0;
    float* hidnew = wsf + o;               o += 4194304;
    unsigned short* us = (unsigned short*)(wsf + o);
    size_t uo = 0;
    unsigned short* wo_hi  = us + uo; uo += 32768;
    unsigned short* wih_hi = us + uo; uo += 98304;
    unsigned short* whh_hi = us + uo; uo += 49152;
    unsigned short* lp_hi  = us + uo; uo += 32768;
    unsigned short* w2_hi  = us + uo; uo += 16384;
    unsigned short* pA_hi  = us + uo; uo += 65536;
    unsigned short* pA_lo  = us + uo; uo += 65536;

    k_prep_wfrag<<<112, 256, 0, stream>>>(W_in, W_out, w_ih, w_hh, lp, W2,
                                          wo_hi, wih_hi, whh_hi, lp_hi, w2_hi);
    k_gnn<<<512, 512, 0, stream>>>(items, Amat, emb, b_in, b_out, b_iah, b_oah,
                                   wo_hi, wih_hi, whh_hi, b_ih, b_hh, hidnew);
    k_tail<<<512, 256, 0, stream>>>(alias, pos, hidnew,
                                    lp_hi, w2_hi, b2,
                                    W1, b1, W3, Wt, bt, pA_hi, pA_lo);
    k_pred_mfma<<<391, 512, 0, stream>>>(pA_hi, pA_lo, emb, outp);
}